// Round 9
// baseline (308.246 us; speedup 1.0000x reference)
//
#include <hip/hip_runtime.h>
#include <hip/hip_bf16.h>

typedef __attribute__((ext_vector_type(8))) short short8;
typedef __attribute__((ext_vector_type(4))) float f32x4;

#define N_NODES 20000
#define N_EDGES 320000
#define NFEAT 512
#define NHID 1024
#define MBTOT 1252   // ceil(20000/16)=1250, +2 pad for the 64-row tail

__device__ __forceinline__ float bf2f(unsigned short u) {
    union { unsigned int i; float f; } c; c.i = ((unsigned int)u) << 16; return c.f;
}
__device__ __forceinline__ unsigned short f2bf(float f) {
    union { float f; unsigned int i; } c; c.f = f;
    unsigned int x = c.i;
    return (unsigned short)((x + 0x7fffu + ((x >> 16) & 1u)) >> 16);
}

// ---------------- CSR build ----------------

__global__ void hist_kernel(const int* __restrict__ dst, int* __restrict__ deg, int E) {
    int e = blockIdx.x * 256 + threadIdx.x;
    if (e < E) atomicAdd(&deg[dst[e]], 1);
}

__global__ __launch_bounds__(1024) void scan_kernel(const int* __restrict__ deg,
                                                    int* __restrict__ row_ptr,
                                                    int* __restrict__ cursor, int n) {
    __shared__ int sdata[1024];
    const int t = threadIdx.x;
    constexpr int CH = 20;
    int base = t * CH;
    int local[CH];
    int sum = 0;
#pragma unroll
    for (int i = 0; i < CH; ++i) {
        int idx = base + i;
        int v = (idx < n) ? deg[idx] : 0;
        local[i] = sum;
        sum += v;
    }
    sdata[t] = sum;
    __syncthreads();
    for (int off = 1; off < 1024; off <<= 1) {
        int v = (t >= off) ? sdata[t - off] : 0;
        __syncthreads();
        sdata[t] += v;
        __syncthreads();
    }
    int prev = (t == 0) ? 0 : sdata[t - 1];
#pragma unroll
    for (int i = 0; i < CH; ++i) {
        int idx = base + i;
        if (idx < n) {
            int p = prev + local[i];
            row_ptr[idx] = p;
            cursor[idx]  = p;
        }
    }
    if (t == 1023) row_ptr[n] = sdata[1023];
}

__global__ void fill_kernel(const int* __restrict__ src, const int* __restrict__ dst,
                            const float* __restrict__ vals, int* __restrict__ cursor,
                            int* __restrict__ csr_src, float* __restrict__ csr_val, int E) {
    int e = blockIdx.x * 256 + threadIdx.x;
    if (e < E) {
        int d = dst[e];
        int pos = atomicAdd(&cursor[d], 1);
        csr_src[pos] = src[e];
        csr_val[pos] = vals[e];
    }
}

// ------------- W transpose + bf16 + MFMA-fragment pack -------------
// W[k][n] (f32, K x N) -> Bp[nb][kb][lane=kq*16+rl][j] = bf16 W[kb*32+kq*8+j][nb*16+rl]

__global__ void transpose_cvt_pk(const float* __restrict__ W, unsigned short* __restrict__ Bp,
                                 int K, int N) {
    __shared__ float tile[32][33];
    const int KT = K >> 5;
    int ntx = N >> 5;
    int k0 = (blockIdx.x / ntx) << 5;
    int n0 = (blockIdx.x % ntx) << 5;
    int tx = threadIdx.x & 31, ty = threadIdx.x >> 5;
#pragma unroll
    for (int i = 0; i < 32; i += 8)
        tile[ty + i][tx] = W[(size_t)(k0 + ty + i) * N + n0 + tx];
    __syncthreads();
#pragma unroll
    for (int i = 0; i < 32; i += 8) {
        int n = n0 + ty + i;
        int k = k0 + tx;
        int nb = n >> 4, rl = n & 15;
        int kb = k >> 5, kq = (k & 31) >> 3, j = k & 7;
        Bp[((((size_t)nb * KT + kb) * 64) + kq * 16 + rl) * 8 + j] = f2bf(tile[tx][ty + i]);
    }
}

// ------------- f32 -> bf16 convert (x) -------------

__global__ void cvt_bf16_kernel(const float* __restrict__ x, unsigned short* __restrict__ xb,
                                int n8) {
    int i = blockIdx.x * 256 + threadIdx.x;
    if (i < n8) {
        f32x4 v0 = ((const f32x4*)x)[i * 2];
        f32x4 v1 = ((const f32x4*)x)[i * 2 + 1];
        short8 o;
#pragma unroll
        for (int j = 0; j < 4; ++j) {
            o[j]     = (short)f2bf(v0[j]);
            o[4 + j] = (short)f2bf(v1[j]);
        }
        ((short8*)xb)[i] = o;
    }
}

// ------------- dropout mask bit-pack: bit=1 iff u > 0.5 (32B/lane) -------------

__global__ __launch_bounds__(256) void mask_kernel(const float* __restrict__ u,
                                                   unsigned int* __restrict__ mask) {
    __shared__ unsigned char nib[256];
    size_t base = (size_t)blockIdx.x * 2048;
    int t = threadIdx.x;
    f32x4 v0 = ((const f32x4*)(u + base))[t * 2];
    f32x4 v1 = ((const f32x4*)(u + base))[t * 2 + 1];
    unsigned n = 0;
#pragma unroll
    for (int j = 0; j < 4; ++j) {
        n |= (v0[j] > 0.5f ? 1u : 0u) << j;
        n |= (v1[j] > 0.5f ? 1u : 0u) << (4 + j);
    }
    nib[t] = (unsigned char)n;
    __syncthreads();
    if (t < 64) {
        unsigned w = (unsigned)nib[t * 4] | ((unsigned)nib[t * 4 + 1] << 8) |
                     ((unsigned)nib[t * 4 + 2] << 16) | ((unsigned)nib[t * 4 + 3] << 24);
        mask[base / 32 + t] = w;
    }
}

// ------------- chunked aggregation 1 -------------
// grid = 4 chunks x 1250 blocks; block = 4 waves; each 16-lane group owns one
// dst node and gathers a 128-feat (256B) slice. Chunk working set = 5 MB -> L2.
// Output: packed A-fragment layout A1p[mb][kb][kq*16+rl][j].

__global__ __launch_bounds__(256) void agg1_kernel(const unsigned short* __restrict__ xbf,
                                                   const int* __restrict__ csr_src,
                                                   const float* __restrict__ csr_val,
                                                   const int* __restrict__ row_ptr,
                                                   unsigned short* __restrict__ A1p) {
    const int c = blockIdx.x / 1250;               // feature chunk 0..3
    const int dbase = (blockIdx.x % 1250) * 16;
    const int wid = threadIdx.x >> 6;
    const int lane = threadIdx.x & 63;
    const int g = lane >> 4;                       // group 0..3
    const int s = lane & 15;                       // slot in group
    const int d = dbase + wid * 4 + g;
    const int e0 = row_ptr[d], e1 = row_ptr[d + 1];
    const size_t fb = c * 128 + s * 8;             // feature offset of this slot

    f32x4 a0 = {0.f, 0.f, 0.f, 0.f}, a1 = {0.f, 0.f, 0.f, 0.f};
    const int glane = g * 16;

    for (int eb = e0; eb < e1; eb += 16) {
        int cnt = e1 - eb; if (cnt > 16) cnt = 16;
        int sv = 0; float fv = 0.f;
        if (s < cnt) { sv = csr_src[eb + s]; fv = csr_val[eb + s]; }
        if (cnt == 16) {
#pragma unroll
            for (int i = 0; i < 16; ++i) {
                int srcn = __shfl(sv, glane + i);
                float val = __shfl(fv, glane + i);
                short8 w = *(const short8*)&xbf[(size_t)srcn * NFEAT + fb];
#pragma unroll
                for (int j = 0; j < 4; ++j) {
                    a0[j] += val * bf2f((unsigned short)w[j]);
                    a1[j] += val * bf2f((unsigned short)w[4 + j]);
                }
            }
        } else {
            for (int i = 0; i < cnt; ++i) {
                int srcn = __shfl(sv, glane + i);
                float val = __shfl(fv, glane + i);
                short8 w = *(const short8*)&xbf[(size_t)srcn * NFEAT + fb];
#pragma unroll
                for (int j = 0; j < 4; ++j) {
                    a0[j] += val * bf2f((unsigned short)w[j]);
                    a1[j] += val * bf2f((unsigned short)w[4 + j]);
                }
            }
        }
    }
    short8 o;
#pragma unroll
    for (int j = 0; j < 4; ++j) {
        o[j]     = (short)f2bf(a0[j]);
        o[4 + j] = (short)f2bf(a1[j]);
    }
    // kb = c*4 + s/4, kq = s%4
    size_t idx = ((((size_t)(d >> 4) * (NFEAT / 32) + (c * 4 + (s >> 2))) * 64) +
                  (s & 3) * 16 + (d & 15)) * 8;
    *(short8*)&A1p[idx] = o;
}

// ------------- chunked aggregation 2 (bf16 in row-major, f32 out + bias) -------------

__global__ __launch_bounds__(256) void agg2_kernel(const unsigned short* __restrict__ s2,
                                                   const int* __restrict__ csr_src,
                                                   const float* __restrict__ csr_val,
                                                   const int* __restrict__ row_ptr,
                                                   const float* __restrict__ b2,
                                                   float* __restrict__ out) {
    const int c = blockIdx.x / 1250;
    const int dbase = (blockIdx.x % 1250) * 16;
    const int wid = threadIdx.x >> 6;
    const int lane = threadIdx.x & 63;
    const int g = lane >> 4;
    const int s = lane & 15;
    const int d = dbase + wid * 4 + g;
    const int e0 = row_ptr[d], e1 = row_ptr[d + 1];
    const size_t fb = c * 128 + s * 8;

    f32x4 a0 = *(const f32x4*)&b2[fb];
    f32x4 a1 = *(const f32x4*)&b2[fb + 4];
    const int glane = g * 16;

    for (int eb = e0; eb < e1; eb += 16) {
        int cnt = e1 - eb; if (cnt > 16) cnt = 16;
        int sv = 0; float fv = 0.f;
        if (s < cnt) { sv = csr_src[eb + s]; fv = csr_val[eb + s]; }
        if (cnt == 16) {
#pragma unroll
            for (int i = 0; i < 16; ++i) {
                int srcn = __shfl(sv, glane + i);
                float val = __shfl(fv, glane + i);
                short8 w = *(const short8*)&s2[(size_t)srcn * NFEAT + fb];
#pragma unroll
                for (int j = 0; j < 4; ++j) {
                    a0[j] += val * bf2f((unsigned short)w[j]);
                    a1[j] += val * bf2f((unsigned short)w[4 + j]);
                }
            }
        } else {
            for (int i = 0; i < cnt; ++i) {
                int srcn = __shfl(sv, glane + i);
                float val = __shfl(fv, glane + i);
                short8 w = *(const short8*)&s2[(size_t)srcn * NFEAT + fb];
#pragma unroll
                for (int j = 0; j < 4; ++j) {
                    a0[j] += val * bf2f((unsigned short)w[j]);
                    a1[j] += val * bf2f((unsigned short)w[4 + j]);
                }
            }
        }
    }
    *(f32x4*)&out[(size_t)d * NFEAT + fb]     = a0;
    *(f32x4*)&out[(size_t)d * NFEAT + fb + 4] = a1;
}

// ------------- fragment-packed register GEMM (2 mi x 2 ni waves) -------------
// Every load = contiguous 1KB wave burst. Waves pair-share A (same mi) and
// B (same ni) through L1. No LDS/barriers in main loop.
// EPI==1: bias+relu+dropout, packed output via wave-private LDS transpose.

template <int EPI, int KT, int NW>
__global__ __launch_bounds__(256, EPI ? 2 : 3) void gemm_pk(
    const unsigned short* __restrict__ Ap,
    const unsigned short* __restrict__ Bp,
    unsigned short* __restrict__ C,
    int M,
    const float* __restrict__ bias,
    const unsigned int* __restrict__ umask) {
    constexpr int N = NW * 64;
    constexpr int MI_MAX = 313;    // ceil(20000/64)

    // bijective XCD swizzle (m204)
    const int nwg = gridDim.x;
    const int bid = blockIdx.x;
    const int q = nwg >> 3, r = nwg & 7;
    const int xcd = bid & 7, pos = bid >> 3;
    const int swz = (xcd < r ? xcd * (q + 1) : r * (q + 1) + (xcd - r) * q) + pos;

    const int wid = threadIdx.x >> 6;
    const int lane = threadIdx.x & 63;
    const int rl = lane & 15;
    const int kq = lane >> 4;

    constexpr int NT2 = NW / 2;
    const int bm = swz / NT2;
    const int bn = swz % NT2;
    int mi = bm * 2 + (wid >> 1); if (mi >= MI_MAX) mi = MI_MAX - 1;  // dup-safe clamp
    const int ni = bn * 2 + (wid & 1);

    const unsigned short* ab = Ap + (size_t)(mi * 4) * KT * 512 + lane * 8;
    const unsigned short* bb = Bp + (size_t)(ni * 4) * KT * 512 + lane * 8;

    f32x4 acc[4][4] = {};

#pragma unroll
    for (int kb = 0; kb < KT; ++kb) {
        short8 af[4], bf[4];
#pragma unroll
        for (int m = 0; m < 4; ++m)
            af[m] = *(const short8*)(ab + ((size_t)m * KT + kb) * 512);
#pragma unroll
        for (int n = 0; n < 4; ++n)
            bf[n] = *(const short8*)(bb + ((size_t)n * KT + kb) * 512);
#pragma unroll
        for (int m = 0; m < 4; ++m)
#pragma unroll
            for (int n = 0; n < 4; ++n)
                acc[m][n] = __builtin_amdgcn_mfma_f32_16x16x32_bf16(af[m], bf[n], acc[m][n], 0, 0, 0);
    }

    if constexpr (EPI == 1) {
        __shared__ float ltr[4][64][36];
        constexpr int KT2 = N / 32;
#pragma unroll
        for (int n2 = 0; n2 < 2; ++n2) {
#pragma unroll
            for (int m = 0; m < 4; ++m) {
#pragma unroll
                for (int nn = 0; nn < 2; ++nn) {
                    int n = n2 * 2 + nn;
                    int gc = ni * 64 + n * 16 + rl;
                    float bv = bias[gc];
#pragma unroll
                    for (int j = 0; j < 4; ++j) {
                        int gr = mi * 64 + m * 16 + kq * 4 + j;
                        int grm = gr < M ? gr : M - 1;
                        float v = acc[m][n][j] + bv;
                        v = v > 0.f ? v : 0.f;
                        unsigned w = umask[(size_t)grm * (N >> 5) + (gc >> 5)];
                        v = ((w >> (gc & 31)) & 1u) ? v * 2.0f : 0.0f;
                        ltr[wid][m * 16 + kq * 4 + j][nn * 16 + rl] = v;
                    }
                }
            }
            __builtin_amdgcn_s_waitcnt(0);
#pragma unroll
            for (int m2 = 0; m2 < 4; ++m2) {
                int row = m2 * 16 + rl;
                f32x4 r0 = *(const f32x4*)&ltr[wid][row][kq * 8];
                f32x4 r1 = *(const f32x4*)&ltr[wid][row][kq * 8 + 4];
                short8 o;
#pragma unroll
                for (int j = 0; j < 4; ++j) {
                    o[j]     = (short)f2bf(r0[j]);
                    o[4 + j] = (short)f2bf(r1[j]);
                }
                int mbg = mi * 4 + m2;
                if (mbg * 16 < M) {
                    size_t dst = (((size_t)mbg * KT2 + (ni * 2 + n2)) * 64 + lane) * 8;
                    *(short8*)&C[dst] = o;
                }
            }
            __builtin_amdgcn_s_waitcnt(0);
        }
    } else {
        const int crow = kq * 4;
#pragma unroll
        for (int m = 0; m < 4; ++m) {
#pragma unroll
            for (int n = 0; n < 4; ++n) {
                int gr0 = mi * 64 + m * 16 + crow;
                int gc = ni * 64 + n * 16 + rl;
#pragma unroll
                for (int j = 0; j < 4; ++j) {
                    int gr = gr0 + j;
                    if (gr < M)
                        C[(size_t)gr * N + gc] = f2bf(acc[m][n][j]);
                }
            }
        }
    }
}

// ---------------- launch ----------------

extern "C" void kernel_launch(void* const* d_in, const int* in_sizes, int n_in,
                              void* d_out, int out_size, void* d_ws, size_t ws_size,
                              hipStream_t stream) {
    const float* x        = (const float*)d_in[0];
    const float* W1       = (const float*)d_in[1];
    const float* b1       = (const float*)d_in[2];
    const float* W2       = (const float*)d_in[3];
    const float* b2       = (const float*)d_in[4];
    const float* adj_vals = (const float*)d_in[5];
    const float* u_drop   = (const float*)d_in[6];
    const int*   src      = (const int*)d_in[7];
    const int*   dst      = (const int*)d_in[8];
    float* out = (float*)d_out;

    char* p = (char*)d_ws;
    auto take = [&](size_t bytes) {
        char* q = p;
        p += (bytes + 255) & ~(size_t)255;
        return q;
    };
    int* deg        = (int*)take((size_t)N_NODES * 4);
    int* row_ptr    = (int*)take((size_t)(N_NODES + 1) * 4);
    int* cursor     = (int*)take((size_t)N_NODES * 4);
    int* csr_src    = (int*)take((size_t)N_EDGES * 4);
    float* csr_val  = (float*)take((size_t)N_EDGES * 4);
    unsigned short* w1p   = (unsigned short*)take((size_t)NFEAT * NHID * 2);
    unsigned short* w2p   = (unsigned short*)take((size_t)NFEAT * NHID * 2);
    unsigned short* xbf   = (unsigned short*)take((size_t)N_NODES * NFEAT * 2);
    unsigned short* a1p   = (unsigned short*)take((size_t)MBTOT * (NFEAT / 32) * 1024);
    unsigned short* a2p   = (unsigned short*)take((size_t)MBTOT * (NHID / 32) * 1024);
    unsigned short* s2buf = (unsigned short*)take((size_t)N_NODES * NFEAT * 2);
    unsigned int* umask   = (unsigned int*)take((size_t)N_NODES * (NHID / 32) * 4);

    hipMemsetAsync(deg, 0, (size_t)N_NODES * 4, stream);
    hist_kernel<<<(N_EDGES + 255) / 256, 256, 0, stream>>>(dst, deg, N_EDGES);
    scan_kernel<<<1, 1024, 0, stream>>>(deg, row_ptr, cursor, N_NODES);
    fill_kernel<<<(N_EDGES + 255) / 256, 256, 0, stream>>>(src, dst, adj_vals, cursor,
                                                           csr_src, csr_val, N_EDGES);
    transpose_cvt_pk<<<(NFEAT / 32) * (NHID / 32), 256, 0, stream>>>(W1, w1p, NFEAT, NHID);
    transpose_cvt_pk<<<(NHID / 32) * (NFEAT / 32), 256, 0, stream>>>(W2, w2p, NHID, NFEAT);
    cvt_bf16_kernel<<<(N_NODES * NFEAT / 8 + 255) / 256, 256, 0, stream>>>(
        x, xbf, N_NODES * NFEAT / 8);
    mask_kernel<<<N_NODES * NHID / 2048, 256, 0, stream>>>(u_drop, umask);

    agg1_kernel<<<4 * 1250, 256, 0, stream>>>(xbf, csr_src, csr_val, row_ptr, a1p);

    // GEMM1: [20000,512] x [512,1024] -> packed a2p
    gemm_pk<1, NFEAT / 32, NHID / 64><<<157 * (NHID / 128), 256, 0, stream>>>(
        a1p, w1p, a2p, N_NODES, b1, umask);
    // GEMM2: [20000,1024] x [1024,512] -> row-major s2buf
    gemm_pk<0, NHID / 32, NFEAT / 64><<<157 * (NFEAT / 128), 256, 0, stream>>>(
        a2p, w2p, s2buf, N_NODES, nullptr, nullptr);

    agg2_kernel<<<4 * 1250, 256, 0, stream>>>(s2buf, csr_src, csr_val, row_ptr, b2, out);
}

// Round 10
// 299.697 us; speedup vs baseline: 1.0285x; 1.0285x over previous
//
#include <hip/hip_runtime.h>
#include <hip/hip_bf16.h>

typedef __attribute__((ext_vector_type(8))) short short8;
typedef __attribute__((ext_vector_type(4))) float f32x4;

#define N_NODES 20000
#define N_EDGES 320000
#define NFEAT 512
#define NHID 1024
#define MBTOT 1252

__device__ __forceinline__ float bf2f(unsigned short u) {
    union { unsigned int i; float f; } c; c.i = ((unsigned int)u) << 16; return c.f;
}
__device__ __forceinline__ unsigned short f2bf(float f) {
    union { float f; unsigned int i; } c; c.f = f;
    unsigned int x = c.i;
    return (unsigned short)((x + 0x7fffu + ((x >> 16) & 1u)) >> 16);
}

// ---------------- CSR build ----------------

__global__ void hist_kernel(const int* __restrict__ dst, int* __restrict__ deg, int E) {
    int e = blockIdx.x * 256 + threadIdx.x;
    if (e < E) atomicAdd(&deg[dst[e]], 1);
}

__global__ __launch_bounds__(1024) void scan_kernel(const int* __restrict__ deg,
                                                    int* __restrict__ row_ptr,
                                                    int* __restrict__ cursor, int n) {
    __shared__ int sdata[1024];
    const int t = threadIdx.x;
    constexpr int CH = 20;
    int base = t * CH;
    int local[CH];
    int sum = 0;
#pragma unroll
    for (int i = 0; i < CH; ++i) {
        int idx = base + i;
        int v = (idx < n) ? deg[idx] : 0;
        local[i] = sum;
        sum += v;
    }
    sdata[t] = sum;
    __syncthreads();
    for (int off = 1; off < 1024; off <<= 1) {
        int v = (t >= off) ? sdata[t - off] : 0;
        __syncthreads();
        sdata[t] += v;
        __syncthreads();
    }
    int prev = (t == 0) ? 0 : sdata[t - 1];
#pragma unroll
    for (int i = 0; i < CH; ++i) {
        int idx = base + i;
        if (idx < n) {
            int p = prev + local[i];
            row_ptr[idx] = p;
            cursor[idx]  = p;
        }
    }
    if (t == 1023) row_ptr[n] = sdata[1023];
}

// csr_off stores BYTE offsets (src * NFEAT * 2 = src * 1024), fits int32
__global__ void fill_kernel(const int* __restrict__ src, const int* __restrict__ dst,
                            const float* __restrict__ vals, int* __restrict__ cursor,
                            int* __restrict__ csr_off, float* __restrict__ csr_val, int E) {
    int e = blockIdx.x * 256 + threadIdx.x;
    if (e < E) {
        int d = dst[e];
        int pos = atomicAdd(&cursor[d], 1);
        csr_off[pos] = src[e] << 10;
        csr_val[pos] = vals[e];
    }
}

// ------------- W transpose + bf16 + MFMA-fragment pack -------------

__global__ void transpose_cvt_pk(const float* __restrict__ W, unsigned short* __restrict__ Bp,
                                 int K, int N) {
    __shared__ float tile[32][33];
    const int KT = K >> 5;
    int ntx = N >> 5;
    int k0 = (blockIdx.x / ntx) << 5;
    int n0 = (blockIdx.x % ntx) << 5;
    int tx = threadIdx.x & 31, ty = threadIdx.x >> 5;
#pragma unroll
    for (int i = 0; i < 32; i += 8)
        tile[ty + i][tx] = W[(size_t)(k0 + ty + i) * N + n0 + tx];
    __syncthreads();
#pragma unroll
    for (int i = 0; i < 32; i += 8) {
        int n = n0 + ty + i;
        int k = k0 + tx;
        int nb = n >> 4, rl = n & 15;
        int kb = k >> 5, kq = (k & 31) >> 3, j = k & 7;
        Bp[((((size_t)nb * KT + kb) * 64) + kq * 16 + rl) * 8 + j] = f2bf(tile[tx][ty + i]);
    }
}

// ------------- f32 -> bf16 convert (x) -------------

__global__ void cvt_bf16_kernel(const float* __restrict__ x, unsigned short* __restrict__ xb,
                                int n8) {
    int i = blockIdx.x * 256 + threadIdx.x;
    if (i < n8) {
        f32x4 v0 = ((const f32x4*)x)[i * 2];
        f32x4 v1 = ((const f32x4*)x)[i * 2 + 1];
        short8 o;
#pragma unroll
        for (int j = 0; j < 4; ++j) {
            o[j]     = (short)f2bf(v0[j]);
            o[4 + j] = (short)f2bf(v1[j]);
        }
        ((short8*)xb)[i] = o;
    }
}

// ------------- dropout mask bit-pack (32B/lane) -------------

__global__ __launch_bounds__(256) void mask_kernel(const float* __restrict__ u,
                                                   unsigned int* __restrict__ mask) {
    __shared__ unsigned char nib[256];
    size_t base = (size_t)blockIdx.x * 2048;
    int t = threadIdx.x;
    f32x4 v0 = ((const f32x4*)(u + base))[t * 2];
    f32x4 v1 = ((const f32x4*)(u + base))[t * 2 + 1];
    unsigned n = 0;
#pragma unroll
    for (int j = 0; j < 4; ++j) {
        n |= (v0[j] > 0.5f ? 1u : 0u) << j;
        n |= (v1[j] > 0.5f ? 1u : 0u) << (4 + j);
    }
    nib[t] = (unsigned char)n;
    __syncthreads();
    if (t < 64) {
        unsigned w = (unsigned)nib[t * 4] | ((unsigned)nib[t * 4 + 1] << 8) |
                     ((unsigned)nib[t * 4 + 2] << 16) | ((unsigned)nib[t * 4 + 3] << 24);
        mask[base / 32 + t] = w;
    }
}

// ------------- chunked aggregation 1 (8 chunks x 64 feats, 2.5 MB WS -> L2) -------------
// 8-lane groups: group owns one dst; lane s handles feats c*64+s*8 (16B burst).
// Output: packed A-fragment layout.

__global__ __launch_bounds__(256) void agg1_kernel(const unsigned short* __restrict__ xbf,
                                                   const int* __restrict__ csr_off,
                                                   const float* __restrict__ csr_val,
                                                   const int* __restrict__ row_ptr,
                                                   unsigned short* __restrict__ A1p) {
    const int c = blockIdx.x / 625;                // chunk 0..7
    const int dbase = (blockIdx.x % 625) * 32;
    const int wid = threadIdx.x >> 6;
    const int lane = threadIdx.x & 63;
    const int g = lane >> 3;                       // group 0..7
    const int s = lane & 7;
    const int d = dbase + wid * 8 + g;
    const int e0 = row_ptr[d], e1 = row_ptr[d + 1];
    const char* xc = (const char*)xbf + (c * 64 + s * 8) * 2;

    f32x4 a0 = {0.f, 0.f, 0.f, 0.f}, a1 = {0.f, 0.f, 0.f, 0.f};
    const int glane = g * 8;

    for (int eb = e0; eb < e1; eb += 8) {
        int cnt = e1 - eb; if (cnt > 8) cnt = 8;
        int ov = 0; float fv = 0.f;
        if (s < cnt) { ov = csr_off[eb + s]; fv = csr_val[eb + s]; }
        if (cnt == 8) {
#pragma unroll
            for (int i = 0; i < 8; ++i) {
                int off = __shfl(ov, glane + i);
                float val = __shfl(fv, glane + i);
                short8 w = *(const short8*)(xc + off);
#pragma unroll
                for (int j = 0; j < 4; ++j) {
                    a0[j] += val * bf2f((unsigned short)w[j]);
                    a1[j] += val * bf2f((unsigned short)w[4 + j]);
                }
            }
        } else {
            for (int i = 0; i < cnt; ++i) {
                int off = __shfl(ov, glane + i);
                float val = __shfl(fv, glane + i);
                short8 w = *(const short8*)(xc + off);
#pragma unroll
                for (int j = 0; j < 4; ++j) {
                    a0[j] += val * bf2f((unsigned short)w[j]);
                    a1[j] += val * bf2f((unsigned short)w[4 + j]);
                }
            }
        }
    }
    short8 o;
#pragma unroll
    for (int j = 0; j < 4; ++j) {
        o[j]     = (short)f2bf(a0[j]);
        o[4 + j] = (short)f2bf(a1[j]);
    }
    // kb = c*2 + s/4, kq = s%4
    size_t idx = ((((size_t)(d >> 4) * (NFEAT / 32) + (c * 2 + (s >> 2))) * 64) +
                  (s & 3) * 16 + (d & 15)) * 8;
    *(short8*)&A1p[idx] = o;
}

// ------------- chunked aggregation 2 (8 chunks x 64 feats; bf16 in, f32+bias out) -------------

__global__ __launch_bounds__(256) void agg2_kernel(const unsigned short* __restrict__ s2,
                                                   const int* __restrict__ csr_off,
                                                   const float* __restrict__ csr_val,
                                                   const int* __restrict__ row_ptr,
                                                   const float* __restrict__ b2,
                                                   float* __restrict__ out) {
    const int c = blockIdx.x / 625;
    const int dbase = (blockIdx.x % 625) * 32;
    const int wid = threadIdx.x >> 6;
    const int lane = threadIdx.x & 63;
    const int g = lane >> 3;
    const int s = lane & 7;
    const int d = dbase + wid * 8 + g;
    const int e0 = row_ptr[d], e1 = row_ptr[d + 1];
    const int fb = c * 64 + s * 8;
    const char* xc = (const char*)s2 + fb * 2;

    f32x4 a0 = *(const f32x4*)&b2[fb];
    f32x4 a1 = *(const f32x4*)&b2[fb + 4];
    const int glane = g * 8;

    for (int eb = e0; eb < e1; eb += 8) {
        int cnt = e1 - eb; if (cnt > 8) cnt = 8;
        int ov = 0; float fv = 0.f;
        if (s < cnt) { ov = csr_off[eb + s]; fv = csr_val[eb + s]; }
        if (cnt == 8) {
#pragma unroll
            for (int i = 0; i < 8; ++i) {
                int off = __shfl(ov, glane + i);
                float val = __shfl(fv, glane + i);
                short8 w = *(const short8*)(xc + off);
#pragma unroll
                for (int j = 0; j < 4; ++j) {
                    a0[j] += val * bf2f((unsigned short)w[j]);
                    a1[j] += val * bf2f((unsigned short)w[4 + j]);
                }
            }
        } else {
            for (int i = 0; i < cnt; ++i) {
                int off = __shfl(ov, glane + i);
                float val = __shfl(fv, glane + i);
                short8 w = *(const short8*)(xc + off);
#pragma unroll
                for (int j = 0; j < 4; ++j) {
                    a0[j] += val * bf2f((unsigned short)w[j]);
                    a1[j] += val * bf2f((unsigned short)w[4 + j]);
                }
            }
        }
    }
    *(f32x4*)&out[(size_t)d * NFEAT + fb]     = a0;
    *(f32x4*)&out[(size_t)d * NFEAT + fb + 4] = a1;
}

// ------------- fragment-packed register GEMM, 2-deep register pipeline -------------
// Loads for kb+1 issue before MFMAs of kb -> MLP across the MFMA cluster.
// EPI==1: bias+relu (write phase) + dropout via coalesced mask word (read phase),
// packed output through wave-private LDS transpose.

template <int EPI, int KT, int NW>
__global__ __launch_bounds__(256, EPI ? 2 : 3) void gemm_pk(
    const unsigned short* __restrict__ Ap,
    const unsigned short* __restrict__ Bp,
    unsigned short* __restrict__ C,
    int M,
    const float* __restrict__ bias,
    const unsigned int* __restrict__ umask) {
    constexpr int N = NW * 64;
    constexpr int MI_MAX = 313;

    // bijective XCD swizzle (m204)
    const int nwg = gridDim.x;
    const int bid = blockIdx.x;
    const int q = nwg >> 3, r = nwg & 7;
    const int xcd = bid & 7, pos = bid >> 3;
    const int swz = (xcd < r ? xcd * (q + 1) : r * (q + 1) + (xcd - r) * q) + pos;

    const int wid = threadIdx.x >> 6;
    const int lane = threadIdx.x & 63;
    const int rl = lane & 15;
    const int kq = lane >> 4;

    constexpr int NT2 = NW / 2;
    const int bm = swz / NT2;
    const int bn = swz % NT2;
    int mi = bm * 2 + (wid >> 1); if (mi >= MI_MAX) mi = MI_MAX - 1;
    const int ni = bn * 2 + (wid & 1);

    const unsigned short* ab = Ap + (size_t)(mi * 4) * KT * 512 + lane * 8;
    const unsigned short* bb = Bp + (size_t)(ni * 4) * KT * 512 + lane * 8;

    f32x4 acc[4][4] = {};
    short8 aX[4], bX[4], aY[4], bY[4];

#pragma unroll
    for (int m = 0; m < 4; ++m) aX[m] = *(const short8*)(ab + (size_t)m * KT * 512);
#pragma unroll
    for (int n = 0; n < 4; ++n) bX[n] = *(const short8*)(bb + (size_t)n * KT * 512);

#pragma unroll
    for (int kb = 0; kb < KT; kb += 2) {
        if (kb + 1 < KT) {
#pragma unroll
            for (int m = 0; m < 4; ++m)
                aY[m] = *(const short8*)(ab + ((size_t)m * KT + kb + 1) * 512);
#pragma unroll
            for (int n = 0; n < 4; ++n)
                bY[n] = *(const short8*)(bb + ((size_t)n * KT + kb + 1) * 512);
        }
#pragma unroll
        for (int m = 0; m < 4; ++m)
#pragma unroll
            for (int n = 0; n < 4; ++n)
                acc[m][n] = __builtin_amdgcn_mfma_f32_16x16x32_bf16(aX[m], bX[n], acc[m][n], 0, 0, 0);
        if (kb + 2 < KT) {
#pragma unroll
            for (int m = 0; m < 4; ++m)
                aX[m] = *(const short8*)(ab + ((size_t)m * KT + kb + 2) * 512);
#pragma unroll
            for (int n = 0; n < 4; ++n)
                bX[n] = *(const short8*)(bb + ((size_t)n * KT + kb + 2) * 512);
        }
        if (kb + 1 < KT) {
#pragma unroll
            for (int m = 0; m < 4; ++m)
#pragma unroll
                for (int n = 0; n < 4; ++n)
                    acc[m][n] = __builtin_amdgcn_mfma_f32_16x16x32_bf16(aY[m], bY[n], acc[m][n], 0, 0, 0);
        }
    }

    if constexpr (EPI == 1) {
        __shared__ float ltr[4][64][36];
        constexpr int KT2 = N / 32;
#pragma unroll
        for (int n2 = 0; n2 < 2; ++n2) {
            // write phase: bias + relu only
#pragma unroll
            for (int m = 0; m < 4; ++m) {
#pragma unroll
                for (int nn = 0; nn < 2; ++nn) {
                    int n = n2 * 2 + nn;
                    float bv = bias[ni * 64 + n * 16 + rl];
#pragma unroll
                    for (int j = 0; j < 4; ++j) {
                        float v = acc[m][n][j] + bv;
                        v = v > 0.f ? v : 0.f;
                        ltr[wid][m * 16 + kq * 4 + j][nn * 16 + rl] = v;
                    }
                }
            }
            __builtin_amdgcn_s_waitcnt(0);
            // read phase: dropout (1 coalesced mask word per row) + pack
#pragma unroll
            for (int m2 = 0; m2 < 4; ++m2) {
                int row = m2 * 16 + rl;
                int gr = mi * 64 + row;
                int grm = gr < M ? gr : M - 1;
                unsigned w = umask[(size_t)grm * (N >> 5) + (ni * 2 + n2)];
                f32x4 r0 = *(const f32x4*)&ltr[wid][row][kq * 8];
                f32x4 r1 = *(const f32x4*)&ltr[wid][row][kq * 8 + 4];
                short8 o;
#pragma unroll
                for (int j = 0; j < 4; ++j) {
                    o[j]     = ((w >> (kq * 8 + j)) & 1u)     ? (short)f2bf(r0[j] * 2.0f) : (short)0;
                    o[4 + j] = ((w >> (kq * 8 + 4 + j)) & 1u) ? (short)f2bf(r1[j] * 2.0f) : (short)0;
                }
                int mbg = mi * 4 + m2;
                if (mbg * 16 < M) {
                    size_t dst = (((size_t)mbg * KT2 + (ni * 2 + n2)) * 64 + lane) * 8;
                    *(short8*)&C[dst] = o;
                }
            }
            __builtin_amdgcn_s_waitcnt(0);
        }
    } else {
        const int crow = kq * 4;
#pragma unroll
        for (int m = 0; m < 4; ++m) {
#pragma unroll
            for (int n = 0; n < 4; ++n) {
                int gr0 = mi * 64 + m * 16 + crow;
                int gc = ni * 64 + n * 16 + rl;
#pragma unroll
                for (int j = 0; j < 4; ++j) {
                    int gr = gr0 + j;
                    if (gr < M)
                        C[(size_t)gr * N + gc] = f2bf(acc[m][n][j]);
                }
            }
        }
    }
}

// ---------------- launch ----------------

extern "C" void kernel_launch(void* const* d_in, const int* in_sizes, int n_in,
                              void* d_out, int out_size, void* d_ws, size_t ws_size,
                              hipStream_t stream) {
    const float* x        = (const float*)d_in[0];
    const float* W1       = (const float*)d_in[1];
    const float* b1       = (const float*)d_in[2];
    const float* W2       = (const float*)d_in[3];
    const float* b2       = (const float*)d_in[4];
    const float* adj_vals = (const float*)d_in[5];
    const float* u_drop   = (const float*)d_in[6];
    const int*   src      = (const int*)d_in[7];
    const int*   dst      = (const int*)d_in[8];
    float* out = (float*)d_out;

    char* p = (char*)d_ws;
    auto take = [&](size_t bytes) {
        char* q = p;
        p += (bytes + 255) & ~(size_t)255;
        return q;
    };
    int* deg        = (int*)take((size_t)N_NODES * 4);
    int* row_ptr    = (int*)take((size_t)(N_NODES + 1) * 4);
    int* cursor     = (int*)take((size_t)N_NODES * 4);
    int* csr_off    = (int*)take((size_t)N_EDGES * 4);
    float* csr_val  = (float*)take((size_t)N_EDGES * 4);
    unsigned short* w1p   = (unsigned short*)take((size_t)NFEAT * NHID * 2);
    unsigned short* w2p   = (unsigned short*)take((size_t)NFEAT * NHID * 2);
    unsigned short* xbf   = (unsigned short*)take((size_t)N_NODES * NFEAT * 2);
    unsigned short* a1p   = (unsigned short*)take((size_t)MBTOT * (NFEAT / 32) * 1024);
    unsigned short* a2p   = (unsigned short*)take((size_t)MBTOT * (NHID / 32) * 1024);
    unsigned short* s2buf = (unsigned short*)take((size_t)N_NODES * NFEAT * 2);
    unsigned int* umask   = (unsigned int*)take((size_t)N_NODES * (NHID / 32) * 4);

    hipMemsetAsync(deg, 0, (size_t)N_NODES * 4, stream);
    hist_kernel<<<(N_EDGES + 255) / 256, 256, 0, stream>>>(dst, deg, N_EDGES);
    scan_kernel<<<1, 1024, 0, stream>>>(deg, row_ptr, cursor, N_NODES);
    fill_kernel<<<(N_EDGES + 255) / 256, 256, 0, stream>>>(src, dst, adj_vals, cursor,
                                                           csr_off, csr_val, N_EDGES);
    transpose_cvt_pk<<<(NFEAT / 32) * (NHID / 32), 256, 0, stream>>>(W1, w1p, NFEAT, NHID);
    transpose_cvt_pk<<<(NHID / 32) * (NFEAT / 32), 256, 0, stream>>>(W2, w2p, NHID, NFEAT);
    cvt_bf16_kernel<<<(N_NODES * NFEAT / 8 + 255) / 256, 256, 0, stream>>>(
        x, xbf, N_NODES * NFEAT / 8);
    mask_kernel<<<N_NODES * NHID / 2048, 256, 0, stream>>>(u_drop, umask);

    agg1_kernel<<<8 * 625, 256, 0, stream>>>(xbf, csr_off, csr_val, row_ptr, a1p);

    // GEMM1: [20000,512] x [512,1024] -> packed a2p
    gemm_pk<1, NFEAT / 32, NHID / 64><<<157 * (NHID / 128), 256, 0, stream>>>(
        a1p, w1p, a2p, N_NODES, b1, umask);
    // GEMM2: [20000,1024] x [1024,512] -> row-major s2buf
    gemm_pk<0, NHID / 32, NFEAT / 64><<<157 * (NFEAT / 128), 256, 0, stream>>>(
        a2p, w2p, s2buf, N_NODES, nullptr, nullptr);

    agg2_kernel<<<8 * 625, 256, 0, stream>>>(s2buf, csr_off, csr_val, row_ptr, b2, out);
}

// Round 11
// 275.945 us; speedup vs baseline: 1.1171x; 1.0861x over previous
//
#include <hip/hip_runtime.h>
#include <hip/hip_bf16.h>

typedef __attribute__((ext_vector_type(8))) short short8;
typedef __attribute__((ext_vector_type(4))) float f32x4;

#define N_NODES 20000
#define N_EDGES 320000
#define NFEAT 512
#define NHID 1024
#define MBTOT 1252

__device__ __forceinline__ float bf2f(unsigned short u) {
    union { unsigned int i; float f; } c; c.i = ((unsigned int)u) << 16; return c.f;
}
__device__ __forceinline__ unsigned short f2bf(float f) {
    union { float f; unsigned int i; } c; c.f = f;
    unsigned int x = c.i;
    return (unsigned short)((x + 0x7fffu + ((x >> 16) & 1u)) >> 16);
}

// ---------------- CSR build ----------------

__global__ void hist_kernel(const int* __restrict__ dst, int* __restrict__ deg, int E) {
    int e = blockIdx.x * 256 + threadIdx.x;
    if (e < E) atomicAdd(&deg[dst[e]], 1);
}

__global__ __launch_bounds__(1024) void scan_kernel(const int* __restrict__ deg,
                                                    int* __restrict__ row_ptr,
                                                    int* __restrict__ cursor, int n) {
    __shared__ int sdata[1024];
    const int t = threadIdx.x;
    constexpr int CH = 20;
    int base = t * CH;
    int local[CH];
    int sum = 0;
#pragma unroll
    for (int i = 0; i < CH; ++i) {
        int idx = base + i;
        int v = (idx < n) ? deg[idx] : 0;
        local[i] = sum;
        sum += v;
    }
    sdata[t] = sum;
    __syncthreads();
    for (int off = 1; off < 1024; off <<= 1) {
        int v = (t >= off) ? sdata[t - off] : 0;
        __syncthreads();
        sdata[t] += v;
        __syncthreads();
    }
    int prev = (t == 0) ? 0 : sdata[t - 1];
#pragma unroll
    for (int i = 0; i < CH; ++i) {
        int idx = base + i;
        if (idx < n) {
            int p = prev + local[i];
            row_ptr[idx] = p;
            cursor[idx]  = p;
        }
    }
    if (t == 1023) row_ptr[n] = sdata[1023];
}

// csr_off stores BYTE offsets (src * NFEAT * 2 = src * 1024), fits int32
__global__ void fill_kernel(const int* __restrict__ src, const int* __restrict__ dst,
                            const float* __restrict__ vals, int* __restrict__ cursor,
                            int* __restrict__ csr_off, float* __restrict__ csr_val, int E) {
    int e = blockIdx.x * 256 + threadIdx.x;
    if (e < E) {
        int d = dst[e];
        int pos = atomicAdd(&cursor[d], 1);
        csr_off[pos] = src[e] << 10;
        csr_val[pos] = vals[e];
    }
}

// ------------- W transpose + bf16 + MFMA-fragment pack -------------

__global__ void transpose_cvt_pk(const float* __restrict__ W, unsigned short* __restrict__ Bp,
                                 int K, int N) {
    __shared__ float tile[32][33];
    const int KT = K >> 5;
    int ntx = N >> 5;
    int k0 = (blockIdx.x / ntx) << 5;
    int n0 = (blockIdx.x % ntx) << 5;
    int tx = threadIdx.x & 31, ty = threadIdx.x >> 5;
#pragma unroll
    for (int i = 0; i < 32; i += 8)
        tile[ty + i][tx] = W[(size_t)(k0 + ty + i) * N + n0 + tx];
    __syncthreads();
#pragma unroll
    for (int i = 0; i < 32; i += 8) {
        int n = n0 + ty + i;
        int k = k0 + tx;
        int nb = n >> 4, rl = n & 15;
        int kb = k >> 5, kq = (k & 31) >> 3, j = k & 7;
        Bp[((((size_t)nb * KT + kb) * 64) + kq * 16 + rl) * 8 + j] = f2bf(tile[tx][ty + i]);
    }
}

// ------------- f32 -> bf16 convert (x) -------------

__global__ void cvt_bf16_kernel(const float* __restrict__ x, unsigned short* __restrict__ xb,
                                int n8) {
    int i = blockIdx.x * 256 + threadIdx.x;
    if (i < n8) {
        f32x4 v0 = ((const f32x4*)x)[i * 2];
        f32x4 v1 = ((const f32x4*)x)[i * 2 + 1];
        short8 o;
#pragma unroll
        for (int j = 0; j < 4; ++j) {
            o[j]     = (short)f2bf(v0[j]);
            o[4 + j] = (short)f2bf(v1[j]);
        }
        ((short8*)xb)[i] = o;
    }
}

// ------------- dropout mask bit-pack (32B/lane) -------------

__global__ __launch_bounds__(256) void mask_kernel(const float* __restrict__ u,
                                                   unsigned int* __restrict__ mask) {
    __shared__ unsigned char nib[256];
    size_t base = (size_t)blockIdx.x * 2048;
    int t = threadIdx.x;
    f32x4 v0 = ((const f32x4*)(u + base))[t * 2];
    f32x4 v1 = ((const f32x4*)(u + base))[t * 2 + 1];
    unsigned n = 0;
#pragma unroll
    for (int j = 0; j < 4; ++j) {
        n |= (v0[j] > 0.5f ? 1u : 0u) << j;
        n |= (v1[j] > 0.5f ? 1u : 0u) << (4 + j);
    }
    nib[t] = (unsigned char)n;
    __syncthreads();
    if (t < 64) {
        unsigned w = (unsigned)nib[t * 4] | ((unsigned)nib[t * 4 + 1] << 8) |
                     ((unsigned)nib[t * 4 + 2] << 16) | ((unsigned)nib[t * 4 + 3] << 24);
        mask[base / 32 + t] = w;
    }
}

// ------------- XCD-pinned chunked aggregation 1 -------------
// chunk = blockIdx & 7 -> lands on XCD (round-robin dispatch): each XCD's L2
// only ever holds ONE 2.5 MB feature slice -> gather becomes L2-hit.
// 8-lane groups: group owns one dst; lane s handles feats c*64+s*8 (16B burst).

__global__ __launch_bounds__(256) void agg1_kernel(const unsigned short* __restrict__ xbf,
                                                   const int* __restrict__ csr_off,
                                                   const float* __restrict__ csr_val,
                                                   const int* __restrict__ row_ptr,
                                                   unsigned short* __restrict__ A1p) {
    const int c = blockIdx.x & 7;                  // chunk == XCD
    const int dbase = (blockIdx.x >> 3) * 32;
    const int wid = threadIdx.x >> 6;
    const int lane = threadIdx.x & 63;
    const int g = lane >> 3;                       // group 0..7
    const int s = lane & 7;
    const int d = dbase + wid * 8 + g;
    const int e0 = row_ptr[d], e1 = row_ptr[d + 1];
    const char* xc = (const char*)xbf + (c * 64 + s * 8) * 2;

    f32x4 a0 = {0.f, 0.f, 0.f, 0.f}, a1 = {0.f, 0.f, 0.f, 0.f};
    const int glane = g * 8;

    for (int eb = e0; eb < e1; eb += 8) {
        int cnt = e1 - eb; if (cnt > 8) cnt = 8;
        int ov = 0; float fv = 0.f;
        if (s < cnt) { ov = csr_off[eb + s]; fv = csr_val[eb + s]; }
        if (cnt == 8) {
#pragma unroll
            for (int i = 0; i < 8; ++i) {
                int off = __shfl(ov, glane + i);
                float val = __shfl(fv, glane + i);
                short8 w = *(const short8*)(xc + off);
#pragma unroll
                for (int j = 0; j < 4; ++j) {
                    a0[j] += val * bf2f((unsigned short)w[j]);
                    a1[j] += val * bf2f((unsigned short)w[4 + j]);
                }
            }
        } else {
            for (int i = 0; i < cnt; ++i) {
                int off = __shfl(ov, glane + i);
                float val = __shfl(fv, glane + i);
                short8 w = *(const short8*)(xc + off);
#pragma unroll
                for (int j = 0; j < 4; ++j) {
                    a0[j] += val * bf2f((unsigned short)w[j]);
                    a1[j] += val * bf2f((unsigned short)w[4 + j]);
                }
            }
        }
    }
    short8 o;
#pragma unroll
    for (int j = 0; j < 4; ++j) {
        o[j]     = (short)f2bf(a0[j]);
        o[4 + j] = (short)f2bf(a1[j]);
    }
    // kb = c*2 + s/4, kq = s%4
    size_t idx = ((((size_t)(d >> 4) * (NFEAT / 32) + (c * 2 + (s >> 2))) * 64) +
                  (s & 3) * 16 + (d & 15)) * 8;
    *(short8*)&A1p[idx] = o;
}

// ------------- XCD-pinned chunked aggregation 2 (bf16 in, f32+bias out) -------------

__global__ __launch_bounds__(256) void agg2_kernel(const unsigned short* __restrict__ s2,
                                                   const int* __restrict__ csr_off,
                                                   const float* __restrict__ csr_val,
                                                   const int* __restrict__ row_ptr,
                                                   const float* __restrict__ b2,
                                                   float* __restrict__ out) {
    const int c = blockIdx.x & 7;                  // chunk == XCD
    const int dbase = (blockIdx.x >> 3) * 32;
    const int wid = threadIdx.x >> 6;
    const int lane = threadIdx.x & 63;
    const int g = lane >> 3;
    const int s = lane & 7;
    const int d = dbase + wid * 8 + g;
    const int e0 = row_ptr[d], e1 = row_ptr[d + 1];
    const int fb = c * 64 + s * 8;
    const char* xc = (const char*)s2 + fb * 2;

    f32x4 a0 = *(const f32x4*)&b2[fb];
    f32x4 a1 = *(const f32x4*)&b2[fb + 4];
    const int glane = g * 8;

    for (int eb = e0; eb < e1; eb += 8) {
        int cnt = e1 - eb; if (cnt > 8) cnt = 8;
        int ov = 0; float fv = 0.f;
        if (s < cnt) { ov = csr_off[eb + s]; fv = csr_val[eb + s]; }
        if (cnt == 8) {
#pragma unroll
            for (int i = 0; i < 8; ++i) {
                int off = __shfl(ov, glane + i);
                float val = __shfl(fv, glane + i);
                short8 w = *(const short8*)(xc + off);
#pragma unroll
                for (int j = 0; j < 4; ++j) {
                    a0[j] += val * bf2f((unsigned short)w[j]);
                    a1[j] += val * bf2f((unsigned short)w[4 + j]);
                }
            }
        } else {
            for (int i = 0; i < cnt; ++i) {
                int off = __shfl(ov, glane + i);
                float val = __shfl(fv, glane + i);
                short8 w = *(const short8*)(xc + off);
#pragma unroll
                for (int j = 0; j < 4; ++j) {
                    a0[j] += val * bf2f((unsigned short)w[j]);
                    a1[j] += val * bf2f((unsigned short)w[4 + j]);
                }
            }
        }
    }
    *(f32x4*)&out[(size_t)d * NFEAT + fb]     = a0;
    *(f32x4*)&out[(size_t)d * NFEAT + fb + 4] = a1;
}

// ------------- fragment-packed register GEMM, 2-deep register pipeline -------------

template <int EPI, int KT, int NW>
__global__ __launch_bounds__(256, EPI ? 2 : 3) void gemm_pk(
    const unsigned short* __restrict__ Ap,
    const unsigned short* __restrict__ Bp,
    unsigned short* __restrict__ C,
    int M,
    const float* __restrict__ bias,
    const unsigned int* __restrict__ umask) {
    constexpr int N = NW * 64;
    constexpr int MI_MAX = 313;

    // bijective XCD swizzle (m204)
    const int nwg = gridDim.x;
    const int bid = blockIdx.x;
    const int q = nwg >> 3, r = nwg & 7;
    const int xcd = bid & 7, pos = bid >> 3;
    const int swz = (xcd < r ? xcd * (q + 1) : r * (q + 1) + (xcd - r) * q) + pos;

    const int wid = threadIdx.x >> 6;
    const int lane = threadIdx.x & 63;
    const int rl = lane & 15;
    const int kq = lane >> 4;

    constexpr int NT2 = NW / 2;
    const int bm = swz / NT2;
    const int bn = swz % NT2;
    int mi = bm * 2 + (wid >> 1); if (mi >= MI_MAX) mi = MI_MAX - 1;
    const int ni = bn * 2 + (wid & 1);

    const unsigned short* ab = Ap + (size_t)(mi * 4) * KT * 512 + lane * 8;
    const unsigned short* bb = Bp + (size_t)(ni * 4) * KT * 512 + lane * 8;

    f32x4 acc[4][4] = {};
    short8 aX[4], bX[4], aY[4], bY[4];

#pragma unroll
    for (int m = 0; m < 4; ++m) aX[m] = *(const short8*)(ab + (size_t)m * KT * 512);
#pragma unroll
    for (int n = 0; n < 4; ++n) bX[n] = *(const short8*)(bb + (size_t)n * KT * 512);

#pragma unroll
    for (int kb = 0; kb < KT; kb += 2) {
        if (kb + 1 < KT) {
#pragma unroll
            for (int m = 0; m < 4; ++m)
                aY[m] = *(const short8*)(ab + ((size_t)m * KT + kb + 1) * 512);
#pragma unroll
            for (int n = 0; n < 4; ++n)
                bY[n] = *(const short8*)(bb + ((size_t)n * KT + kb + 1) * 512);
        }
#pragma unroll
        for (int m = 0; m < 4; ++m)
#pragma unroll
            for (int n = 0; n < 4; ++n)
                acc[m][n] = __builtin_amdgcn_mfma_f32_16x16x32_bf16(aX[m], bX[n], acc[m][n], 0, 0, 0);
        if (kb + 2 < KT) {
#pragma unroll
            for (int m = 0; m < 4; ++m)
                aX[m] = *(const short8*)(ab + ((size_t)m * KT + kb + 2) * 512);
#pragma unroll
            for (int n = 0; n < 4; ++n)
                bX[n] = *(const short8*)(bb + ((size_t)n * KT + kb + 2) * 512);
        }
        if (kb + 1 < KT) {
#pragma unroll
            for (int m = 0; m < 4; ++m)
#pragma unroll
                for (int n = 0; n < 4; ++n)
                    acc[m][n] = __builtin_amdgcn_mfma_f32_16x16x32_bf16(aY[m], bY[n], acc[m][n], 0, 0, 0);
        }
    }

    if constexpr (EPI == 1) {
        __shared__ float ltr[4][64][36];
        constexpr int KT2 = N / 32;
#pragma unroll
        for (int n2 = 0; n2 < 2; ++n2) {
#pragma unroll
            for (int m = 0; m < 4; ++m) {
#pragma unroll
                for (int nn = 0; nn < 2; ++nn) {
                    int n = n2 * 2 + nn;
                    float bv = bias[ni * 64 + n * 16 + rl];
#pragma unroll
                    for (int j = 0; j < 4; ++j) {
                        float v = acc[m][n][j] + bv;
                        v = v > 0.f ? v : 0.f;
                        ltr[wid][m * 16 + kq * 4 + j][nn * 16 + rl] = v;
                    }
                }
            }
            __builtin_amdgcn_s_waitcnt(0);
#pragma unroll
            for (int m2 = 0; m2 < 4; ++m2) {
                int row = m2 * 16 + rl;
                int gr = mi * 64 + row;
                int grm = gr < M ? gr : M - 1;
                unsigned w = umask[(size_t)grm * (N >> 5) + (ni * 2 + n2)];
                f32x4 r0 = *(const f32x4*)&ltr[wid][row][kq * 8];
                f32x4 r1 = *(const f32x4*)&ltr[wid][row][kq * 8 + 4];
                short8 o;
#pragma unroll
                for (int j = 0; j < 4; ++j) {
                    o[j]     = ((w >> (kq * 8 + j)) & 1u)     ? (short)f2bf(r0[j] * 2.0f) : (short)0;
                    o[4 + j] = ((w >> (kq * 8 + 4 + j)) & 1u) ? (short)f2bf(r1[j] * 2.0f) : (short)0;
                }
                int mbg = mi * 4 + m2;
                if (mbg * 16 < M) {
                    size_t dst = (((size_t)mbg * KT2 + (ni * 2 + n2)) * 64 + lane) * 8;
                    *(short8*)&C[dst] = o;
                }
            }
            __builtin_amdgcn_s_waitcnt(0);
        }
    } else {
        const int crow = kq * 4;
#pragma unroll
        for (int m = 0; m < 4; ++m) {
#pragma unroll
            for (int n = 0; n < 4; ++n) {
                int gr0 = mi * 64 + m * 16 + crow;
                int gc = ni * 64 + n * 16 + rl;
#pragma unroll
                for (int j = 0; j < 4; ++j) {
                    int gr = gr0 + j;
                    if (gr < M)
                        C[(size_t)gr * N + gc] = f2bf(acc[m][n][j]);
                }
            }
        }
    }
}

// ---------------- launch ----------------

extern "C" void kernel_launch(void* const* d_in, const int* in_sizes, int n_in,
                              void* d_out, int out_size, void* d_ws, size_t ws_size,
                              hipStream_t stream) {
    const float* x        = (const float*)d_in[0];
    const float* W1       = (const float*)d_in[1];
    const float* b1       = (const float*)d_in[2];
    const float* W2       = (const float*)d_in[3];
    const float* b2       = (const float*)d_in[4];
    const float* adj_vals = (const float*)d_in[5];
    const float* u_drop   = (const float*)d_in[6];
    const int*   src      = (const int*)d_in[7];
    const int*   dst      = (const int*)d_in[8];
    float* out = (float*)d_out;

    char* p = (char*)d_ws;
    auto take = [&](size_t bytes) {
        char* q = p;
        p += (bytes + 255) & ~(size_t)255;
        return q;
    };
    int* deg        = (int*)take((size_t)N_NODES * 4);
    int* row_ptr    = (int*)take((size_t)(N_NODES + 1) * 4);
    int* cursor     = (int*)take((size_t)N_NODES * 4);
    int* csr_off    = (int*)take((size_t)N_EDGES * 4);
    float* csr_val  = (float*)take((size_t)N_EDGES * 4);
    unsigned short* w1p   = (unsigned short*)take((size_t)NFEAT * NHID * 2);
    unsigned short* w2p   = (unsigned short*)take((size_t)NFEAT * NHID * 2);
    unsigned short* xbf   = (unsigned short*)take((size_t)N_NODES * NFEAT * 2);
    unsigned short* a1p   = (unsigned short*)take((size_t)MBTOT * (NFEAT / 32) * 1024);
    unsigned short* a2p   = (unsigned short*)take((size_t)MBTOT * (NHID / 32) * 1024);
    unsigned short* s2buf = (unsigned short*)take((size_t)N_NODES * NFEAT * 2);
    unsigned int* umask   = (unsigned int*)take((size_t)N_NODES * (NHID / 32) * 4);

    hipMemsetAsync(deg, 0, (size_t)N_NODES * 4, stream);
    hist_kernel<<<(N_EDGES + 255) / 256, 256, 0, stream>>>(dst, deg, N_EDGES);
    scan_kernel<<<1, 1024, 0, stream>>>(deg, row_ptr, cursor, N_NODES);
    fill_kernel<<<(N_EDGES + 255) / 256, 256, 0, stream>>>(src, dst, adj_vals, cursor,
                                                           csr_off, csr_val, N_EDGES);
    transpose_cvt_pk<<<(NFEAT / 32) * (NHID / 32), 256, 0, stream>>>(W1, w1p, NFEAT, NHID);
    transpose_cvt_pk<<<(NHID / 32) * (NFEAT / 32), 256, 0, stream>>>(W2, w2p, NHID, NFEAT);
    cvt_bf16_kernel<<<(N_NODES * NFEAT / 8 + 255) / 256, 256, 0, stream>>>(
        x, xbf, N_NODES * NFEAT / 8);
    mask_kernel<<<N_NODES * NHID / 2048, 256, 0, stream>>>(u_drop, umask);

    agg1_kernel<<<8 * 625, 256, 0, stream>>>(xbf, csr_off, csr_val, row_ptr, a1p);

    // GEMM1: [20000,512] x [512,1024] -> packed a2p
    gemm_pk<1, NFEAT / 32, NHID / 64><<<157 * (NHID / 128), 256, 0, stream>>>(
        a1p, w1p, a2p, N_NODES, b1, umask);
    // GEMM2: [20000,1024] x [1024,512] -> row-major s2buf
    gemm_pk<0, NHID / 32, NFEAT / 64><<<157 * (NFEAT / 128), 256, 0, stream>>>(
        a2p, w2p, s2buf, N_NODES, nullptr, nullptr);

    agg2_kernel<<<8 * 625, 256, 0, stream>>>(s2buf, csr_off, csr_val, row_ptr, b2, out);
}

// Round 12
// 258.715 us; speedup vs baseline: 1.1915x; 1.0666x over previous
//
#include <hip/hip_runtime.h>
#include <hip/hip_bf16.h>

typedef __attribute__((ext_vector_type(8))) short short8;
typedef __attribute__((ext_vector_type(4))) float f32x4;

#define N_NODES 20000
#define N_EDGES 320000
#define NFEAT 512
#define NHID 1024
#define MBTOT 1252

__device__ __forceinline__ float bf2f(unsigned short u) {
    union { unsigned int i; float f; } c; c.i = ((unsigned int)u) << 16; return c.f;
}
__device__ __forceinline__ unsigned short f2bf(float f) {
    union { float f; unsigned int i; } c; c.f = f;
    unsigned int x = c.i;
    return (unsigned short)((x + 0x7fffu + ((x >> 16) & 1u)) >> 16);
}

// ---------------- CSR build ----------------

__global__ void hist_kernel(const int* __restrict__ dst, int* __restrict__ deg, int E) {
    int e = blockIdx.x * 256 + threadIdx.x;
    if (e < E) atomicAdd(&deg[dst[e]], 1);
}

__global__ __launch_bounds__(1024) void scan_kernel(const int* __restrict__ deg,
                                                    int* __restrict__ row_ptr,
                                                    int* __restrict__ cursor, int n) {
    __shared__ int sdata[1024];
    const int t = threadIdx.x;
    constexpr int CH = 20;
    int base = t * CH;
    int local[CH];
    int sum = 0;
#pragma unroll
    for (int i = 0; i < CH; ++i) {
        int idx = base + i;
        int v = (idx < n) ? deg[idx] : 0;
        local[i] = sum;
        sum += v;
    }
    sdata[t] = sum;
    __syncthreads();
    for (int off = 1; off < 1024; off <<= 1) {
        int v = (t >= off) ? sdata[t - off] : 0;
        __syncthreads();
        sdata[t] += v;
        __syncthreads();
    }
    int prev = (t == 0) ? 0 : sdata[t - 1];
#pragma unroll
    for (int i = 0; i < CH; ++i) {
        int idx = base + i;
        if (idx < n) {
            int p = prev + local[i];
            row_ptr[idx] = p;
            cursor[idx]  = p;
        }
    }
    if (t == 1023) row_ptr[n] = sdata[1023];
}

// csr_off stores BYTE offsets (src * NFEAT * 2 = src * 1024), fits int32
__global__ void fill_kernel(const int* __restrict__ src, const int* __restrict__ dst,
                            const float* __restrict__ vals, int* __restrict__ cursor,
                            int* __restrict__ csr_off, float* __restrict__ csr_val, int E) {
    int e = blockIdx.x * 256 + threadIdx.x;
    if (e < E) {
        int d = dst[e];
        int pos = atomicAdd(&cursor[d], 1);
        csr_off[pos] = src[e] << 10;
        csr_val[pos] = vals[e];
    }
}

// ------------- W transpose + bf16 + MFMA-fragment pack -------------

__global__ void transpose_cvt_pk(const float* __restrict__ W, unsigned short* __restrict__ Bp,
                                 int K, int N) {
    __shared__ float tile[32][33];
    const int KT = K >> 5;
    int ntx = N >> 5;
    int k0 = (blockIdx.x / ntx) << 5;
    int n0 = (blockIdx.x % ntx) << 5;
    int tx = threadIdx.x & 31, ty = threadIdx.x >> 5;
#pragma unroll
    for (int i = 0; i < 32; i += 8)
        tile[ty + i][tx] = W[(size_t)(k0 + ty + i) * N + n0 + tx];
    __syncthreads();
#pragma unroll
    for (int i = 0; i < 32; i += 8) {
        int n = n0 + ty + i;
        int k = k0 + tx;
        int nb = n >> 4, rl = n & 15;
        int kb = k >> 5, kq = (k & 31) >> 3, j = k & 7;
        Bp[((((size_t)nb * KT + kb) * 64) + kq * 16 + rl) * 8 + j] = f2bf(tile[tx][ty + i]);
    }
}

// ------------- f32 -> bf16 convert (x) -------------

__global__ void cvt_bf16_kernel(const float* __restrict__ x, unsigned short* __restrict__ xb,
                                int n8) {
    int i = blockIdx.x * 256 + threadIdx.x;
    if (i < n8) {
        f32x4 v0 = ((const f32x4*)x)[i * 2];
        f32x4 v1 = ((const f32x4*)x)[i * 2 + 1];
        short8 o;
#pragma unroll
        for (int j = 0; j < 4; ++j) {
            o[j]     = (short)f2bf(v0[j]);
            o[4 + j] = (short)f2bf(v1[j]);
        }
        ((short8*)xb)[i] = o;
    }
}

// ------------- dropout mask bit-pack (32B/lane) -------------

__global__ __launch_bounds__(256) void mask_kernel(const float* __restrict__ u,
                                                   unsigned int* __restrict__ mask) {
    __shared__ unsigned char nib[256];
    size_t base = (size_t)blockIdx.x * 2048;
    int t = threadIdx.x;
    f32x4 v0 = ((const f32x4*)(u + base))[t * 2];
    f32x4 v1 = ((const f32x4*)(u + base))[t * 2 + 1];
    unsigned n = 0;
#pragma unroll
    for (int j = 0; j < 4; ++j) {
        n |= (v0[j] > 0.5f ? 1u : 0u) << j;
        n |= (v1[j] > 0.5f ? 1u : 0u) << (4 + j);
    }
    nib[t] = (unsigned char)n;
    __syncthreads();
    if (t < 64) {
        unsigned w = (unsigned)nib[t * 4] | ((unsigned)nib[t * 4 + 1] << 8) |
                     ((unsigned)nib[t * 4 + 2] << 16) | ((unsigned)nib[t * 4 + 3] << 24);
        mask[base / 32 + t] = w;
    }
}

// ------------- XCD-pinned chunked aggregation 1 (packed output) -------------

__global__ __launch_bounds__(256) void agg1_kernel(const unsigned short* __restrict__ xbf,
                                                   const int* __restrict__ csr_off,
                                                   const float* __restrict__ csr_val,
                                                   const int* __restrict__ row_ptr,
                                                   unsigned short* __restrict__ A1p) {
    const int c = blockIdx.x & 7;                  // chunk == XCD
    const int dbase = (blockIdx.x >> 3) * 32;
    const int wid = threadIdx.x >> 6;
    const int lane = threadIdx.x & 63;
    const int g = lane >> 3;
    const int s = lane & 7;
    const int d = dbase + wid * 8 + g;
    const int e0 = row_ptr[d], e1 = row_ptr[d + 1];
    const char* xc = (const char*)xbf + (c * 64 + s * 8) * 2;

    f32x4 a0 = {0.f, 0.f, 0.f, 0.f}, a1 = {0.f, 0.f, 0.f, 0.f};
    const int glane = g * 8;

    for (int eb = e0; eb < e1; eb += 8) {
        int cnt = e1 - eb; if (cnt > 8) cnt = 8;
        int ov = 0; float fv = 0.f;
        if (s < cnt) { ov = csr_off[eb + s]; fv = csr_val[eb + s]; }
        if (cnt == 8) {
#pragma unroll
            for (int i = 0; i < 8; ++i) {
                int off = __shfl(ov, glane + i);
                float val = __shfl(fv, glane + i);
                short8 w = *(const short8*)(xc + off);
#pragma unroll
                for (int j = 0; j < 4; ++j) {
                    a0[j] += val * bf2f((unsigned short)w[j]);
                    a1[j] += val * bf2f((unsigned short)w[4 + j]);
                }
            }
        } else {
            for (int i = 0; i < cnt; ++i) {
                int off = __shfl(ov, glane + i);
                float val = __shfl(fv, glane + i);
                short8 w = *(const short8*)(xc + off);
#pragma unroll
                for (int j = 0; j < 4; ++j) {
                    a0[j] += val * bf2f((unsigned short)w[j]);
                    a1[j] += val * bf2f((unsigned short)w[4 + j]);
                }
            }
        }
    }
    short8 o;
#pragma unroll
    for (int j = 0; j < 4; ++j) {
        o[j]     = (short)f2bf(a0[j]);
        o[4 + j] = (short)f2bf(a1[j]);
    }
    size_t idx = ((((size_t)(d >> 4) * (NFEAT / 32) + (c * 2 + (s >> 2))) * 64) +
                  (s & 3) * 16 + (d & 15)) * 8;
    *(short8*)&A1p[idx] = o;
}

// ------------- XCD-pinned chunked aggregation 2 (bf16 in, f32+bias out) -------------

__global__ __launch_bounds__(256) void agg2_kernel(const unsigned short* __restrict__ s2,
                                                   const int* __restrict__ csr_off,
                                                   const float* __restrict__ csr_val,
                                                   const int* __restrict__ row_ptr,
                                                   const float* __restrict__ b2,
                                                   float* __restrict__ out) {
    const int c = blockIdx.x & 7;
    const int dbase = (blockIdx.x >> 3) * 32;
    const int wid = threadIdx.x >> 6;
    const int lane = threadIdx.x & 63;
    const int g = lane >> 3;
    const int s = lane & 7;
    const int d = dbase + wid * 8 + g;
    const int e0 = row_ptr[d], e1 = row_ptr[d + 1];
    const int fb = c * 64 + s * 8;
    const char* xc = (const char*)s2 + fb * 2;

    f32x4 a0 = *(const f32x4*)&b2[fb];
    f32x4 a1 = *(const f32x4*)&b2[fb + 4];
    const int glane = g * 8;

    for (int eb = e0; eb < e1; eb += 8) {
        int cnt = e1 - eb; if (cnt > 8) cnt = 8;
        int ov = 0; float fv = 0.f;
        if (s < cnt) { ov = csr_off[eb + s]; fv = csr_val[eb + s]; }
        if (cnt == 8) {
#pragma unroll
            for (int i = 0; i < 8; ++i) {
                int off = __shfl(ov, glane + i);
                float val = __shfl(fv, glane + i);
                short8 w = *(const short8*)(xc + off);
#pragma unroll
                for (int j = 0; j < 4; ++j) {
                    a0[j] += val * bf2f((unsigned short)w[j]);
                    a1[j] += val * bf2f((unsigned short)w[4 + j]);
                }
            }
        } else {
            for (int i = 0; i < cnt; ++i) {
                int off = __shfl(ov, glane + i);
                float val = __shfl(fv, glane + i);
                short8 w = *(const short8*)(xc + off);
#pragma unroll
                for (int j = 0; j < 4; ++j) {
                    a0[j] += val * bf2f((unsigned short)w[j]);
                    a1[j] += val * bf2f((unsigned short)w[4 + j]);
                }
            }
        }
    }
    *(f32x4*)&out[(size_t)d * NFEAT + fb]     = a0;
    *(f32x4*)&out[(size_t)d * NFEAT + fb + 4] = a1;
}

// ------------- fragment-packed register GEMM, 32x64 wave tile, 2-deep pipeline -------------
// TM=2: wave tile = 32 (M) x 64 (N); 2x the wave count of 64x64 for TLP.
// #pragma unroll 1 keeps the loop body compact (low VGPR, clean scheduling).
// EPI==1: bias+relu (LDS write) + dropout via coalesced mask word (read), packed out.

template <int EPI, int KT, int NW>
__global__ __launch_bounds__(256, 4) void gemm_pk(
    const unsigned short* __restrict__ Ap,
    const unsigned short* __restrict__ Bp,
    unsigned short* __restrict__ C,
    int M,
    const float* __restrict__ bias,
    const unsigned int* __restrict__ umask) {
    constexpr int N = NW * 64;
    constexpr int MI_MAX = 625;    // 20000/32 exactly

    // bijective XCD swizzle (m204)
    const int nwg = gridDim.x;
    const int bid = blockIdx.x;
    const int q = nwg >> 3, r = nwg & 7;
    const int xcd = bid & 7, pos = bid >> 3;
    const int swz = (xcd < r ? xcd * (q + 1) : r * (q + 1) + (xcd - r) * q) + pos;

    const int wid = threadIdx.x >> 6;
    const int lane = threadIdx.x & 63;
    const int rl = lane & 15;
    const int kq = lane >> 4;

    constexpr int NT2 = NW / 2;
    const int bm = swz / NT2;
    const int bn = swz % NT2;
    int mi = bm * 2 + (wid >> 1); if (mi >= MI_MAX) mi = MI_MAX - 1;  // dup-safe
    const int ni = bn * 2 + (wid & 1);

    const unsigned short* ab = Ap + (size_t)(mi * 2) * KT * 512 + lane * 8;
    const unsigned short* bb = Bp + (size_t)(ni * 4) * KT * 512 + lane * 8;

    f32x4 acc[2][4] = {};
    short8 aX[2], bX[4], aY[2], bY[4];

#pragma unroll
    for (int m = 0; m < 2; ++m) aX[m] = *(const short8*)(ab + (size_t)m * KT * 512);
#pragma unroll
    for (int n = 0; n < 4; ++n) bX[n] = *(const short8*)(bb + (size_t)n * KT * 512);

#pragma unroll 1
    for (int kb = 0; kb < KT; kb += 2) {
        // prefetch kb+1 (always valid: KT even)
#pragma unroll
        for (int m = 0; m < 2; ++m)
            aY[m] = *(const short8*)(ab + ((size_t)m * KT + kb + 1) * 512);
#pragma unroll
        for (int n = 0; n < 4; ++n)
            bY[n] = *(const short8*)(bb + ((size_t)n * KT + kb + 1) * 512);
#pragma unroll
        for (int m = 0; m < 2; ++m)
#pragma unroll
            for (int n = 0; n < 4; ++n)
                acc[m][n] = __builtin_amdgcn_mfma_f32_16x16x32_bf16(aX[m], bX[n], acc[m][n], 0, 0, 0);
        if (kb + 2 < KT) {
#pragma unroll
            for (int m = 0; m < 2; ++m)
                aX[m] = *(const short8*)(ab + ((size_t)m * KT + kb + 2) * 512);
#pragma unroll
            for (int n = 0; n < 4; ++n)
                bX[n] = *(const short8*)(bb + ((size_t)n * KT + kb + 2) * 512);
        }
#pragma unroll
        for (int m = 0; m < 2; ++m)
#pragma unroll
            for (int n = 0; n < 4; ++n)
                acc[m][n] = __builtin_amdgcn_mfma_f32_16x16x32_bf16(aY[m], bY[n], acc[m][n], 0, 0, 0);
    }

    if constexpr (EPI == 1) {
        // bf16 transpose buffer, padded row stride 40 ushorts (80B, 16B-aligned)
        __shared__ unsigned short ltr[4][32][40];
        constexpr int KT2 = N / 32;
#pragma unroll
        for (int n2 = 0; n2 < 2; ++n2) {
            // write phase: bias + relu, bf16
#pragma unroll
            for (int m = 0; m < 2; ++m) {
#pragma unroll
                for (int nn = 0; nn < 2; ++nn) {
                    int n = n2 * 2 + nn;
                    float bv = bias[ni * 64 + n * 16 + rl];
#pragma unroll
                    for (int j = 0; j < 4; ++j) {
                        float v = acc[m][n][j] + bv;
                        v = v > 0.f ? v : 0.f;
                        ltr[wid][m * 16 + kq * 4 + j][nn * 16 + rl] = f2bf(v);
                    }
                }
            }
            __builtin_amdgcn_s_waitcnt(0);  // wave-private LDS: writes visible
            // read phase: dropout via 1 coalesced mask word/row, pack
#pragma unroll
            for (int m2 = 0; m2 < 2; ++m2) {
                int row = m2 * 16 + rl;
                int gr = mi * 32 + row;
                unsigned w = umask[(size_t)gr * (N >> 5) + (ni * 2 + n2)];
                short8 u = *(const short8*)&ltr[wid][row][kq * 8];
                short8 o;
#pragma unroll
                for (int j = 0; j < 4; ++j) {
                    o[j]     = ((w >> (kq * 8 + j)) & 1u)
                               ? (short)f2bf(bf2f((unsigned short)u[j]) * 2.0f) : (short)0;
                    o[4 + j] = ((w >> (kq * 8 + 4 + j)) & 1u)
                               ? (short)f2bf(bf2f((unsigned short)u[4 + j]) * 2.0f) : (short)0;
                }
                int mbg = mi * 2 + m2;
                size_t dst = (((size_t)mbg * KT2 + (ni * 2 + n2)) * 64 + lane) * 8;
                *(short8*)&C[dst] = o;
            }
            __builtin_amdgcn_s_waitcnt(0);  // reads done before next n2 overwrites
        }
    } else {
        const int crow = kq * 4;
#pragma unroll
        for (int m = 0; m < 2; ++m) {
#pragma unroll
            for (int n = 0; n < 4; ++n) {
                int gr0 = mi * 32 + m * 16 + crow;
                int gc = ni * 64 + n * 16 + rl;
#pragma unroll
                for (int j = 0; j < 4; ++j) {
                    int gr = gr0 + j;
                    if (gr < M)
                        C[(size_t)gr * N + gc] = f2bf(acc[m][n][j]);
                }
            }
        }
    }
}

// ---------------- launch ----------------

extern "C" void kernel_launch(void* const* d_in, const int* in_sizes, int n_in,
                              void* d_out, int out_size, void* d_ws, size_t ws_size,
                              hipStream_t stream) {
    const float* x        = (const float*)d_in[0];
    const float* W1       = (const float*)d_in[1];
    const float* b1       = (const float*)d_in[2];
    const float* W2       = (const float*)d_in[3];
    const float* b2       = (const float*)d_in[4];
    const float* adj_vals = (const float*)d_in[5];
    const float* u_drop   = (const float*)d_in[6];
    const int*   src      = (const int*)d_in[7];
    const int*   dst      = (const int*)d_in[8];
    float* out = (float*)d_out;

    char* p = (char*)d_ws;
    auto take = [&](size_t bytes) {
        char* q = p;
        p += (bytes + 255) & ~(size_t)255;
        return q;
    };
    int* deg        = (int*)take((size_t)N_NODES * 4);
    int* row_ptr    = (int*)take((size_t)(N_NODES + 1) * 4);
    int* cursor     = (int*)take((size_t)N_NODES * 4);
    int* csr_off    = (int*)take((size_t)N_EDGES * 4);
    float* csr_val  = (float*)take((size_t)N_EDGES * 4);
    unsigned short* w1p   = (unsigned short*)take((size_t)NFEAT * NHID * 2);
    unsigned short* w2p   = (unsigned short*)take((size_t)NFEAT * NHID * 2);
    unsigned short* xbf   = (unsigned short*)take((size_t)N_NODES * NFEAT * 2);
    unsigned short* a1p   = (unsigned short*)take((size_t)MBTOT * (NFEAT / 32) * 1024);
    unsigned short* a2p   = (unsigned short*)take((size_t)MBTOT * (NHID / 32) * 1024);
    unsigned short* s2buf = (unsigned short*)take((size_t)N_NODES * NFEAT * 2);
    unsigned int* umask   = (unsigned int*)take((size_t)N_NODES * (NHID / 32) * 4);

    hipMemsetAsync(deg, 0, (size_t)N_NODES * 4, stream);
    hist_kernel<<<(N_EDGES + 255) / 256, 256, 0, stream>>>(dst, deg, N_EDGES);
    scan_kernel<<<1, 1024, 0, stream>>>(deg, row_ptr, cursor, N_NODES);
    fill_kernel<<<(N_EDGES + 255) / 256, 256, 0, stream>>>(src, dst, adj_vals, cursor,
                                                           csr_off, csr_val, N_EDGES);
    transpose_cvt_pk<<<(NFEAT / 32) * (NHID / 32), 256, 0, stream>>>(W1, w1p, NFEAT, NHID);
    transpose_cvt_pk<<<(NHID / 32) * (NFEAT / 32), 256, 0, stream>>>(W2, w2p, NHID, NFEAT);
    cvt_bf16_kernel<<<(N_NODES * NFEAT / 8 + 255) / 256, 256, 0, stream>>>(
        x, xbf, N_NODES * NFEAT / 8);
    mask_kernel<<<N_NODES * NHID / 2048, 256, 0, stream>>>(u_drop, umask);

    agg1_kernel<<<8 * 625, 256, 0, stream>>>(xbf, csr_off, csr_val, row_ptr, a1p);

    // GEMM1: [20000,512] x [512,1024] -> packed a2p.  313 bm x 8 bn = 2504 blocks
    gemm_pk<1, NFEAT / 32, NHID / 64><<<313 * (NHID / 128), 256, 0, stream>>>(
        a1p, w1p, a2p, N_NODES, b1, umask);
    // GEMM2: [20000,1024] x [1024,512] -> row-major s2buf. 313 x 4 = 1252 blocks
    gemm_pk<0, NHID / 32, NFEAT / 64><<<313 * (NFEAT / 128), 256, 0, stream>>>(
        a2p, w2p, s2buf, N_NODES, nullptr, nullptr);

    agg2_kernel<<<8 * 625, 256, 0, stream>>>(s2buf, csr_off, csr_val, row_ptr, b2, out);
}

// Round 13
// 232.036 us; speedup vs baseline: 1.3284x; 1.1150x over previous
//
#include <hip/hip_runtime.h>
#include <hip/hip_bf16.h>

typedef __attribute__((ext_vector_type(8))) short short8;
typedef __attribute__((ext_vector_type(4))) float f32x4;

#define N_NODES 20000
#define N_EDGES 320000
#define NFEAT 512
#define NHID 1024
#define MBTOT 1252
#define SCAN_NB 79   // ceil(20000/256)

__device__ __forceinline__ float bf2f(unsigned short u) {
    union { unsigned int i; float f; } c; c.i = ((unsigned int)u) << 16; return c.f;
}
__device__ __forceinline__ unsigned short f2bf(float f) {
    union { float f; unsigned int i; } c; c.f = f;
    unsigned int x = c.i;
    return (unsigned short)((x + 0x7fffu + ((x >> 16) & 1u)) >> 16);
}

// ---------------- CSR build ----------------

__global__ void hist_kernel(const int* __restrict__ dst, int* __restrict__ deg, int E) {
    int e = blockIdx.x * 256 + threadIdx.x;
    if (e < E) atomicAdd(&deg[dst[e]], 1);
}

// hierarchical scan: A (per-256 block scan), B (scan of partials), C (add + cursor)
__global__ __launch_bounds__(256) void scan_a(const int* __restrict__ deg,
                                              int* __restrict__ rp,
                                              int* __restrict__ part, int n) {
    __shared__ int sd[256];
    int t = threadIdx.x;
    int i = blockIdx.x * 256 + t;
    int v = (i < n) ? deg[i] : 0;
    int acc = v;
    sd[t] = acc;
    __syncthreads();
    for (int off = 1; off < 256; off <<= 1) {
        int u = (t >= off) ? sd[t - off] : 0;
        __syncthreads();
        acc += u;
        sd[t] = acc;
        __syncthreads();
    }
    if (i < n) rp[i] = acc - v;          // exclusive within block
    if (t == 255) part[blockIdx.x] = acc; // block total
}

__global__ __launch_bounds__(256) void scan_b(int* __restrict__ part, int nb) {
    __shared__ int sd[256];
    int t = threadIdx.x;
    int v = (t < nb) ? part[t] : 0;
    int acc = v;
    sd[t] = acc;
    __syncthreads();
    for (int off = 1; off < 256; off <<= 1) {
        int u = (t >= off) ? sd[t - off] : 0;
        __syncthreads();
        acc += u;
        sd[t] = acc;
        __syncthreads();
    }
    if (t < nb) part[t] = acc - v;       // exclusive
    if (t == 255) part[nb] = acc;        // grand total
}

__global__ __launch_bounds__(256) void scan_c(int* __restrict__ rp, int* __restrict__ cursor,
                                              const int* __restrict__ part, int n, int nb) {
    int i = blockIdx.x * 256 + threadIdx.x;
    if (i < n) {
        int v = rp[i] + part[blockIdx.x];
        rp[i] = v;
        cursor[i] = v;
    }
    if (i == 0) rp[n] = part[nb];
}

// csr_ov packs (byte-offset = src*1024, val bits) into one int2
__global__ void fill_kernel(const int* __restrict__ src, const int* __restrict__ dst,
                            const float* __restrict__ vals, int* __restrict__ cursor,
                            int2* __restrict__ csr_ov, int E) {
    int e = blockIdx.x * 256 + threadIdx.x;
    if (e < E) {
        int d = dst[e];
        int pos = atomicAdd(&cursor[d], 1);
        csr_ov[pos] = make_int2(src[e] << 10, __float_as_int(vals[e]));
    }
}

// ------------- W transpose + bf16 + MFMA-fragment pack (both weights, one launch) -------------

__device__ __forceinline__ void transpose_body(const float* __restrict__ W,
                                               unsigned short* __restrict__ Bp,
                                               int K, int N, int bid) {
    __shared__ float tile[32][33];
    const int KT = K >> 5;
    int ntx = N >> 5;
    int k0 = (bid / ntx) << 5;
    int n0 = (bid % ntx) << 5;
    int tx = threadIdx.x & 31, ty = threadIdx.x >> 5;
#pragma unroll
    for (int i = 0; i < 32; i += 8)
        tile[ty + i][tx] = W[(size_t)(k0 + ty + i) * N + n0 + tx];
    __syncthreads();
#pragma unroll
    for (int i = 0; i < 32; i += 8) {
        int n = n0 + ty + i;
        int k = k0 + tx;
        int nb = n >> 4, rl = n & 15;
        int kb = k >> 5, kq = (k & 31) >> 3, j = k & 7;
        Bp[((((size_t)nb * KT + kb) * 64) + kq * 16 + rl) * 8 + j] = f2bf(tile[tx][ty + i]);
    }
}

__global__ __launch_bounds__(256) void transpose2_kernel(const float* __restrict__ W1,
                                                         unsigned short* __restrict__ w1p,
                                                         const float* __restrict__ W2,
                                                         unsigned short* __restrict__ w2p) {
    if (blockIdx.x < 512) transpose_body(W1, w1p, NFEAT, NHID, blockIdx.x);
    else                  transpose_body(W2, w2p, NHID, NFEAT, blockIdx.x - 512);
}

// ------------- merged prep: x->bf16 cvt (blocks 0..4999) + mask pack (blocks 5000..14999) -------------

__global__ __launch_bounds__(256) void prep_kernel(const float* __restrict__ x,
                                                   unsigned short* __restrict__ xb,
                                                   const float* __restrict__ u,
                                                   unsigned int* __restrict__ mask) {
    __shared__ unsigned char nib[256];
    int b = blockIdx.x;
    int t = threadIdx.x;
    if (b < 5000) {
        int i = b * 256 + t;   // 1.28M short8 total
        f32x4 v0 = ((const f32x4*)x)[i * 2];
        f32x4 v1 = ((const f32x4*)x)[i * 2 + 1];
        short8 o;
#pragma unroll
        for (int j = 0; j < 4; ++j) {
            o[j]     = (short)f2bf(v0[j]);
            o[4 + j] = (short)f2bf(v1[j]);
        }
        ((short8*)xb)[i] = o;
    } else {
        size_t base = (size_t)(b - 5000) * 2048;
        f32x4 v0 = ((const f32x4*)(u + base))[t * 2];
        f32x4 v1 = ((const f32x4*)(u + base))[t * 2 + 1];
        unsigned n = 0;
#pragma unroll
        for (int j = 0; j < 4; ++j) {
            n |= (v0[j] > 0.5f ? 1u : 0u) << j;
            n |= (v1[j] > 0.5f ? 1u : 0u) << (4 + j);
        }
        nib[t] = (unsigned char)n;
        __syncthreads();
        if (t < 64) {
            unsigned w = (unsigned)nib[t * 4] | ((unsigned)nib[t * 4 + 1] << 8) |
                         ((unsigned)nib[t * 4 + 2] << 16) | ((unsigned)nib[t * 4 + 3] << 24);
            mask[base / 32 + t] = w;
        }
    }
}

// ------------- XCD-pinned chunked aggregation 1 (packed output) -------------
// 2-deep csr pipeline + batched gathers (8 loads in flight before fma).

__global__ __launch_bounds__(256) void agg1_kernel(const unsigned short* __restrict__ xbf,
                                                   const int2* __restrict__ csr_ov,
                                                   const int* __restrict__ row_ptr,
                                                   unsigned short* __restrict__ A1p) {
    const int c = blockIdx.x & 7;                  // chunk == XCD
    const int dbase = (blockIdx.x >> 3) * 32;
    const int wid = threadIdx.x >> 6;
    const int lane = threadIdx.x & 63;
    const int g = lane >> 3;
    const int s = lane & 7;
    const int d = dbase + wid * 8 + g;
    const int e0 = row_ptr[d], e1 = row_ptr[d + 1];
    const char* xc = (const char*)xbf + (c * 64 + s * 8) * 2;
    const int glane = g * 8;

    f32x4 a0 = {0.f, 0.f, 0.f, 0.f}, a1 = {0.f, 0.f, 0.f, 0.f};

    int offX = 0; float valX = 0.f;
    if (e0 + s < e1) { int2 t = csr_ov[e0 + s]; offX = t.x; valX = __int_as_float(t.y); }

    for (int eb = e0; eb < e1; eb += 8) {
        int offY = 0; float valY = 0.f;
        if (eb + 8 + s < e1) { int2 t = csr_ov[eb + 8 + s]; offY = t.x; valY = __int_as_float(t.y); }
        int cnt = e1 - eb; if (cnt > 8) cnt = 8;
        if (cnt == 8) {
            short8 w[8];
#pragma unroll
            for (int i = 0; i < 8; ++i)
                w[i] = *(const short8*)(xc + __shfl(offX, glane + i));
#pragma unroll
            for (int i = 0; i < 8; ++i) {
                float val = __shfl(valX, glane + i);
#pragma unroll
                for (int j = 0; j < 4; ++j) {
                    a0[j] += val * bf2f((unsigned short)w[i][j]);
                    a1[j] += val * bf2f((unsigned short)w[i][4 + j]);
                }
            }
        } else {
            for (int i = 0; i < cnt; ++i) {
                int off = __shfl(offX, glane + i);
                float val = __shfl(valX, glane + i);
                short8 w = *(const short8*)(xc + off);
#pragma unroll
                for (int j = 0; j < 4; ++j) {
                    a0[j] += val * bf2f((unsigned short)w[j]);
                    a1[j] += val * bf2f((unsigned short)w[4 + j]);
                }
            }
        }
        offX = offY; valX = valY;
    }
    short8 o;
#pragma unroll
    for (int j = 0; j < 4; ++j) {
        o[j]     = (short)f2bf(a0[j]);
        o[4 + j] = (short)f2bf(a1[j]);
    }
    size_t idx = ((((size_t)(d >> 4) * (NFEAT / 32) + (c * 2 + (s >> 2))) * 64) +
                  (s & 3) * 16 + (d & 15)) * 8;
    *(short8*)&A1p[idx] = o;
}

// ------------- XCD-pinned chunked aggregation 2 (bf16 in, f32+bias out) -------------

__global__ __launch_bounds__(256) void agg2_kernel(const unsigned short* __restrict__ s2,
                                                   const int2* __restrict__ csr_ov,
                                                   const int* __restrict__ row_ptr,
                                                   const float* __restrict__ b2,
                                                   float* __restrict__ out) {
    const int c = blockIdx.x & 7;
    const int dbase = (blockIdx.x >> 3) * 32;
    const int wid = threadIdx.x >> 6;
    const int lane = threadIdx.x & 63;
    const int g = lane >> 3;
    const int s = lane & 7;
    const int d = dbase + wid * 8 + g;
    const int e0 = row_ptr[d], e1 = row_ptr[d + 1];
    const int fb = c * 64 + s * 8;
    const char* xc = (const char*)s2 + fb * 2;
    const int glane = g * 8;

    f32x4 a0 = *(const f32x4*)&b2[fb];
    f32x4 a1 = *(const f32x4*)&b2[fb + 4];

    int offX = 0; float valX = 0.f;
    if (e0 + s < e1) { int2 t = csr_ov[e0 + s]; offX = t.x; valX = __int_as_float(t.y); }

    for (int eb = e0; eb < e1; eb += 8) {
        int offY = 0; float valY = 0.f;
        if (eb + 8 + s < e1) { int2 t = csr_ov[eb + 8 + s]; offY = t.x; valY = __int_as_float(t.y); }
        int cnt = e1 - eb; if (cnt > 8) cnt = 8;
        if (cnt == 8) {
            short8 w[8];
#pragma unroll
            for (int i = 0; i < 8; ++i)
                w[i] = *(const short8*)(xc + __shfl(offX, glane + i));
#pragma unroll
            for (int i = 0; i < 8; ++i) {
                float val = __shfl(valX, glane + i);
#pragma unroll
                for (int j = 0; j < 4; ++j) {
                    a0[j] += val * bf2f((unsigned short)w[i][j]);
                    a1[j] += val * bf2f((unsigned short)w[i][4 + j]);
                }
            }
        } else {
            for (int i = 0; i < cnt; ++i) {
                int off = __shfl(offX, glane + i);
                float val = __shfl(valX, glane + i);
                short8 w = *(const short8*)(xc + off);
#pragma unroll
                for (int j = 0; j < 4; ++j) {
                    a0[j] += val * bf2f((unsigned short)w[j]);
                    a1[j] += val * bf2f((unsigned short)w[4 + j]);
                }
            }
        }
        offX = offY; valX = valY;
    }
    *(f32x4*)&out[(size_t)d * NFEAT + fb]     = a0;
    *(f32x4*)&out[(size_t)d * NFEAT + fb + 4] = a1;
}

// ------------- fragment-packed register GEMM, 32x64 wave tile, 2-deep pipeline -------------

template <int EPI, int KT, int NW>
__global__ __launch_bounds__(256, 4) void gemm_pk(
    const unsigned short* __restrict__ Ap,
    const unsigned short* __restrict__ Bp,
    unsigned short* __restrict__ C,
    int M,
    const float* __restrict__ bias,
    const unsigned int* __restrict__ umask) {
    constexpr int N = NW * 64;
    constexpr int MI_MAX = 625;

    const int nwg = gridDim.x;
    const int bid = blockIdx.x;
    const int q = nwg >> 3, r = nwg & 7;
    const int xcd = bid & 7, pos = bid >> 3;
    const int swz = (xcd < r ? xcd * (q + 1) : r * (q + 1) + (xcd - r) * q) + pos;

    const int wid = threadIdx.x >> 6;
    const int lane = threadIdx.x & 63;
    const int rl = lane & 15;
    const int kq = lane >> 4;

    constexpr int NT2 = NW / 2;
    const int bm = swz / NT2;
    const int bn = swz % NT2;
    int mi = bm * 2 + (wid >> 1); if (mi >= MI_MAX) mi = MI_MAX - 1;
    const int ni = bn * 2 + (wid & 1);

    const unsigned short* ab = Ap + (size_t)(mi * 2) * KT * 512 + lane * 8;
    const unsigned short* bb = Bp + (size_t)(ni * 4) * KT * 512 + lane * 8;

    f32x4 acc[2][4] = {};
    short8 aX[2], bX[4], aY[2], bY[4];

#pragma unroll
    for (int m = 0; m < 2; ++m) aX[m] = *(const short8*)(ab + (size_t)m * KT * 512);
#pragma unroll
    for (int n = 0; n < 4; ++n) bX[n] = *(const short8*)(bb + (size_t)n * KT * 512);

#pragma unroll 1
    for (int kb = 0; kb < KT; kb += 2) {
#pragma unroll
        for (int m = 0; m < 2; ++m)
            aY[m] = *(const short8*)(ab + ((size_t)m * KT + kb + 1) * 512);
#pragma unroll
        for (int n = 0; n < 4; ++n)
            bY[n] = *(const short8*)(bb + ((size_t)n * KT + kb + 1) * 512);
#pragma unroll
        for (int m = 0; m < 2; ++m)
#pragma unroll
            for (int n = 0; n < 4; ++n)
                acc[m][n] = __builtin_amdgcn_mfma_f32_16x16x32_bf16(aX[m], bX[n], acc[m][n], 0, 0, 0);
        if (kb + 2 < KT) {
#pragma unroll
            for (int m = 0; m < 2; ++m)
                aX[m] = *(const short8*)(ab + ((size_t)m * KT + kb + 2) * 512);
#pragma unroll
            for (int n = 0; n < 4; ++n)
                bX[n] = *(const short8*)(bb + ((size_t)n * KT + kb + 2) * 512);
        }
#pragma unroll
        for (int m = 0; m < 2; ++m)
#pragma unroll
            for (int n = 0; n < 4; ++n)
                acc[m][n] = __builtin_amdgcn_mfma_f32_16x16x32_bf16(aY[m], bY[n], acc[m][n], 0, 0, 0);
    }

    if constexpr (EPI == 1) {
        __shared__ unsigned short ltr[4][32][40];
        constexpr int KT2 = N / 32;
#pragma unroll
        for (int n2 = 0; n2 < 2; ++n2) {
#pragma unroll
            for (int m = 0; m < 2; ++m) {
#pragma unroll
                for (int nn = 0; nn < 2; ++nn) {
                    int n = n2 * 2 + nn;
                    float bv = bias[ni * 64 + n * 16 + rl];
#pragma unroll
                    for (int j = 0; j < 4; ++j) {
                        float v = acc[m][n][j] + bv;
                        v = v > 0.f ? v : 0.f;
                        ltr[wid][m * 16 + kq * 4 + j][nn * 16 + rl] = f2bf(v);
                    }
                }
            }
            __builtin_amdgcn_s_waitcnt(0);
#pragma unroll
            for (int m2 = 0; m2 < 2; ++m2) {
                int row = m2 * 16 + rl;
                int gr = mi * 32 + row;
                unsigned w = umask[(size_t)gr * (N >> 5) + (ni * 2 + n2)];
                short8 u = *(const short8*)&ltr[wid][row][kq * 8];
                short8 o;
#pragma unroll
                for (int j = 0; j < 4; ++j) {
                    o[j]     = ((w >> (kq * 8 + j)) & 1u)
                               ? (short)f2bf(bf2f((unsigned short)u[j]) * 2.0f) : (short)0;
                    o[4 + j] = ((w >> (kq * 8 + 4 + j)) & 1u)
                               ? (short)f2bf(bf2f((unsigned short)u[4 + j]) * 2.0f) : (short)0;
                }
                int mbg = mi * 2 + m2;
                size_t dst = (((size_t)mbg * KT2 + (ni * 2 + n2)) * 64 + lane) * 8;
                *(short8*)&C[dst] = o;
            }
            __builtin_amdgcn_s_waitcnt(0);
        }
    } else {
        const int crow = kq * 4;
#pragma unroll
        for (int m = 0; m < 2; ++m) {
#pragma unroll
            for (int n = 0; n < 4; ++n) {
                int gr0 = mi * 32 + m * 16 + crow;
                int gc = ni * 64 + n * 16 + rl;
#pragma unroll
                for (int j = 0; j < 4; ++j) {
                    int gr = gr0 + j;
                    if (gr < M)
                        C[(size_t)gr * N + gc] = f2bf(acc[m][n][j]);
                }
            }
        }
    }
}

// ---------------- launch ----------------

extern "C" void kernel_launch(void* const* d_in, const int* in_sizes, int n_in,
                              void* d_out, int out_size, void* d_ws, size_t ws_size,
                              hipStream_t stream) {
    const float* x        = (const float*)d_in[0];
    const float* W1       = (const float*)d_in[1];
    const float* b1       = (const float*)d_in[2];
    const float* W2       = (const float*)d_in[3];
    const float* b2       = (const float*)d_in[4];
    const float* adj_vals = (const float*)d_in[5];
    const float* u_drop   = (const float*)d_in[6];
    const int*   src      = (const int*)d_in[7];
    const int*   dst      = (const int*)d_in[8];
    float* out = (float*)d_out;

    char* p = (char*)d_ws;
    auto take = [&](size_t bytes) {
        char* q = p;
        p += (bytes + 255) & ~(size_t)255;
        return q;
    };
    int* deg        = (int*)take((size_t)N_NODES * 4);
    int* row_ptr    = (int*)take((size_t)(N_NODES + 1) * 4);
    int* cursor     = (int*)take((size_t)N_NODES * 4);
    int* part       = (int*)take((size_t)(SCAN_NB + 1) * 4);
    int2* csr_ov    = (int2*)take((size_t)N_EDGES * 8);
    unsigned short* w1p   = (unsigned short*)take((size_t)NFEAT * NHID * 2);
    unsigned short* w2p   = (unsigned short*)take((size_t)NFEAT * NHID * 2);
    unsigned short* xbf   = (unsigned short*)take((size_t)N_NODES * NFEAT * 2);
    unsigned short* a1p   = (unsigned short*)take((size_t)MBTOT * (NFEAT / 32) * 1024);
    unsigned short* a2p   = (unsigned short*)take((size_t)MBTOT * (NHID / 32) * 1024);
    unsigned short* s2buf = (unsigned short*)take((size_t)N_NODES * NFEAT * 2);
    unsigned int* umask   = (unsigned int*)take((size_t)N_NODES * (NHID / 32) * 4);

    hipMemsetAsync(deg, 0, (size_t)N_NODES * 4, stream);
    hist_kernel<<<(N_EDGES + 255) / 256, 256, 0, stream>>>(dst, deg, N_EDGES);
    scan_a<<<SCAN_NB, 256, 0, stream>>>(deg, row_ptr, part, N_NODES);
    scan_b<<<1, 256, 0, stream>>>(part, SCAN_NB);
    scan_c<<<SCAN_NB, 256, 0, stream>>>(row_ptr, cursor, part, N_NODES, SCAN_NB);
    fill_kernel<<<(N_EDGES + 255) / 256, 256, 0, stream>>>(src, dst, adj_vals, cursor,
                                                           csr_ov, N_EDGES);
    transpose2_kernel<<<1024, 256, 0, stream>>>(W1, w1p, W2, w2p);
    prep_kernel<<<15000, 256, 0, stream>>>(x, xbf, u_drop, umask);

    agg1_kernel<<<8 * 625, 256, 0, stream>>>(xbf, csr_ov, row_ptr, a1p);

    gemm_pk<1, NFEAT / 32, NHID / 64><<<313 * (NHID / 128), 256, 0, stream>>>(
        a1p, w1p, a2p, N_NODES, b1, umask);
    gemm_pk<0, NHID / 32, NFEAT / 64><<<313 * (NFEAT / 128), 256, 0, stream>>>(
        a2p, w2p, s2buf, N_NODES, nullptr, nullptr);

    agg2_kernel<<<8 * 625, 256, 0, stream>>>(s2buf, csr_ov, row_ptr, b2, out);
}